// Round 1
// baseline (370.954 us; speedup 1.0000x reference)
//
#include <hip/hip_runtime.h>
#include <math.h>

#define BB 8
#define LL 512
#define CIN 7
#define MARKN 4
#define DM 512
#define DI 1024
#define DSN 16
#define NOUTC 672

// ---------------- stats: mean/std over L per (b,c), write normalized xn ----------------
__global__ __launch_bounds__(64) void k_stats(const float* __restrict__ xe,
    float* __restrict__ mean, float* __restrict__ stdv, float* __restrict__ xn){
  int bc = blockIdx.x;                 // 56
  int b = bc / CIN, c = bc % CIN;
  int t = threadIdx.x;                 // 64
  const float* base = xe + (b*LL)*CIN + c;
  float v[8]; float s = 0.f;
  #pragma unroll
  for(int i=0;i<8;i++){ v[i] = base[(t + i*64)*CIN]; s += v[i]; }
  #pragma unroll
  for(int o=32;o>=1;o>>=1) s += __shfl_down(s, o);
  float m = __shfl(s, 0) * (1.0f/LL);
  float vs = 0.f;
  #pragma unroll
  for(int i=0;i<8;i++){ float dv = v[i]-m; vs += dv*dv; }
  #pragma unroll
  for(int o=32;o>=1;o>>=1) vs += __shfl_down(vs, o);
  float var = __shfl(vs, 0) * (1.0f/LL);
  float sd = sqrtf(var + 1e-5f);
  float inv = 1.0f / sd;
  if(t == 0){ mean[bc] = m; stdv[bc] = sd; }
  float* xnb = xn + (b*LL)*CIN + c;
  #pragma unroll
  for(int i=0;i<8;i++) xnb[(t + i*64)*CIN] = (v[i]-m)*inv;
}

// ---------------- embedding: token conv (wrap pad) + temporal proj + PE ----------------
__global__ __launch_bounds__(512) void k_embed(const float* __restrict__ xn,
    const float* __restrict__ xmark, const float* __restrict__ tw,
    const float* __restrict__ tpw, float* __restrict__ xo){
  __shared__ float sw[DM*21];          // token_conv_w staged (43KB)
  __shared__ float sxr[10][CIN];       // xn rows l0-1 .. l0+8 (wrap)
  __shared__ float smr[8][MARKN];
  int blk = blockIdx.x;                // 512 = 8 b * 64 chunks
  int b = blk >> 6;
  int l0 = (blk & 63) << 3;            // 8 l per block
  int tid = threadIdx.x;
  for(int i=tid; i<DM*21; i+=512) sw[i] = tw[i];
  if(tid < 70){
    int r = tid / CIN, c = tid % CIN;
    int ls = (l0 - 1 + r + LL) % LL;
    sxr[r][c] = xn[(b*LL + ls)*CIN + c];
  } else if(tid >= 128 && tid < 160){
    int i2 = tid - 128; int r = i2 >> 2, m = i2 & 3;
    smr[r][m] = xmark[(b*LL + l0 + r)*MARKN + m];
  }
  __syncthreads();
  int d = tid;
  float wv[21];
  #pragma unroll
  for(int i=0;i<21;i++) wv[i] = sw[d*21 + i];
  float tv[4];
  #pragma unroll
  for(int m=0;m<4;m++) tv[m] = tpw[d*MARKN + m];
  // PE: div = exp(2i * (-ln(10000)/512)), i = d>>1
  float divv = expf((float)(2*(d>>1)) * (-0.0179889460390159843f));
  bool isodd = (d & 1) != 0;
  #pragma unroll
  for(int ll=0; ll<8; ll++){
    float acc = 0.f;
    #pragma unroll
    for(int c=0;c<CIN;c++){
      #pragma unroll
      for(int k=0;k<3;k++) acc += sxr[ll+k][c] * wv[c*3+k];
    }
    #pragma unroll
    for(int m=0;m<4;m++) acc += smr[ll][m] * tv[m];
    float ang = (float)(l0+ll) * divv;
    acc += isodd ? cosf(ang) : sinf(ang);
    xo[(b*LL + l0 + ll)*DM + d] = acc;
  }
}

// ---------------- in_proj GEMM: xz[4096][2048] = x[4096][512] @ W[2048][512]^T ----------------
__global__ __launch_bounds__(256) void k_inproj(const float* __restrict__ A,
    const float* __restrict__ W, float* __restrict__ C){
  __shared__ __align__(16) float As[16][68];
  __shared__ __align__(16) float Bs[16][68];
  int tid = threadIdx.x;
  int m0 = blockIdx.y * 64, n0 = blockIdx.x * 64;
  int tx = tid & 15, ty = tid >> 4;
  int lrow = tid >> 2, lk = (tid & 3) * 4;
  float acc[4][4] = {};
  for(int k0 = 0; k0 < 512; k0 += 16){
    float4 av = *(const float4*)(A + (m0+lrow)*512 + k0 + lk);
    float4 bv = *(const float4*)(W + (n0+lrow)*512 + k0 + lk);
    As[lk+0][lrow]=av.x; As[lk+1][lrow]=av.y; As[lk+2][lrow]=av.z; As[lk+3][lrow]=av.w;
    Bs[lk+0][lrow]=bv.x; Bs[lk+1][lrow]=bv.y; Bs[lk+2][lrow]=bv.z; Bs[lk+3][lrow]=bv.w;
    __syncthreads();
    #pragma unroll
    for(int k=0;k<16;k++){
      float4 ar4 = *(const float4*)&As[k][ty*4];
      float4 br4 = *(const float4*)&Bs[k][tx*4];
      float arr[4] = {ar4.x, ar4.y, ar4.z, ar4.w};
      float brr[4] = {br4.x, br4.y, br4.z, br4.w};
      #pragma unroll
      for(int i=0;i<4;i++)
        #pragma unroll
        for(int j=0;j<4;j++) acc[i][j] += arr[i]*brr[j];
    }
    __syncthreads();
  }
  #pragma unroll
  for(int i=0;i<4;i++){
    float4 cv = make_float4(acc[i][0],acc[i][1],acc[i][2],acc[i][3]);
    *(float4*)(C + (size_t)(m0+ty*4+i)*2048 + n0 + tx*4) = cv;
  }
}

// ---------------- causal depthwise conv (D_CONV=4) + silu -> u ----------------
__global__ __launch_bounds__(1024) void k_dwconv(const float* __restrict__ xz,
    const float* __restrict__ cw, const float* __restrict__ cb, float* __restrict__ u){
  int bl = blockIdx.x;                 // 4096
  int b = bl >> 9, l = bl & 511;
  int d = threadIdx.x;                 // 1024
  const float4 w4 = *(const float4*)(cw + d*4);
  const float* base = xz + (size_t)(b*LL)*2048 + d;
  float acc = cb[d];
  if(l >= 3) acc += base[(size_t)(l-3)*2048] * w4.x;
  if(l >= 2) acc += base[(size_t)(l-2)*2048] * w4.y;
  if(l >= 1) acc += base[(size_t)(l-1)*2048] * w4.z;
  acc += base[(size_t)l*2048] * w4.w;
  float s = acc / (1.f + expf(-acc));
  u[(size_t)bl*1024 + d] = s;
}

// ---------------- x_proj GEMM: dbl[4096][64] = u[4096][1024] @ W[64][1024]^T ----------------
__global__ __launch_bounds__(256) void k_xproj(const float* __restrict__ A,
    const float* __restrict__ W, float* __restrict__ C){
  __shared__ __align__(16) float As[16][36];
  __shared__ __align__(16) float Bs[16][68];
  int tid = threadIdx.x;
  int m0 = blockIdx.y * 32;            // 128 blocks
  int tx = tid & 15, ty = tid >> 4;
  int arow = tid >> 3, ak = (tid & 7) * 2;
  int brow = tid >> 2, bk = (tid & 3) * 4;
  float acc[2][4] = {};
  for(int k0=0;k0<1024;k0+=16){
    float2 av = *(const float2*)(A + (size_t)(m0+arow)*1024 + k0 + ak);
    float4 bv = *(const float4*)(W + (size_t)brow*1024 + k0 + bk);
    As[ak][arow]=av.x; As[ak+1][arow]=av.y;
    Bs[bk+0][brow]=bv.x; Bs[bk+1][brow]=bv.y; Bs[bk+2][brow]=bv.z; Bs[bk+3][brow]=bv.w;
    __syncthreads();
    #pragma unroll
    for(int k=0;k<16;k++){
      float a0 = As[k][ty*2], a1 = As[k][ty*2+1];
      float4 br4 = *(const float4*)&Bs[k][tx*4];
      float brr[4] = {br4.x, br4.y, br4.z, br4.w};
      #pragma unroll
      for(int j=0;j<4;j++){ acc[0][j] += a0*brr[j]; acc[1][j] += a1*brr[j]; }
    }
    __syncthreads();
  }
  #pragma unroll
  for(int i=0;i<2;i++){
    float4 cv = make_float4(acc[i][0],acc[i][1],acc[i][2],acc[i][3]);
    *(float4*)(C + (size_t)(m0+ty*2+i)*64 + tx*4) = cv;
  }
}

// ---------------- dt_proj + softplus: dt[4096][1024] ----------------
__global__ __launch_bounds__(256) void k_dtproj(const float* __restrict__ dbl,
    const float* __restrict__ W, const float* __restrict__ bias, float* __restrict__ dt){
  __shared__ __align__(16) float As[32][68];
  __shared__ __align__(16) float Bs[32][68];
  int tid = threadIdx.x;
  int n0 = blockIdx.x * 64, m0 = blockIdx.y * 64;
  int tx = tid & 15, ty = tid >> 4;
  int row = tid >> 2, lk = (tid & 3) * 8;
  {
    float4 a0 = *(const float4*)(dbl + (size_t)(m0+row)*64 + lk);
    float4 a1 = *(const float4*)(dbl + (size_t)(m0+row)*64 + lk + 4);
    As[lk+0][row]=a0.x; As[lk+1][row]=a0.y; As[lk+2][row]=a0.z; As[lk+3][row]=a0.w;
    As[lk+4][row]=a1.x; As[lk+5][row]=a1.y; As[lk+6][row]=a1.z; As[lk+7][row]=a1.w;
    float4 b0 = *(const float4*)(W + (size_t)(n0+row)*32 + lk);
    float4 b1 = *(const float4*)(W + (size_t)(n0+row)*32 + lk + 4);
    Bs[lk+0][row]=b0.x; Bs[lk+1][row]=b0.y; Bs[lk+2][row]=b0.z; Bs[lk+3][row]=b0.w;
    Bs[lk+4][row]=b1.x; Bs[lk+5][row]=b1.y; Bs[lk+6][row]=b1.z; Bs[lk+7][row]=b1.w;
  }
  __syncthreads();
  float acc[4][4] = {};
  #pragma unroll
  for(int k=0;k<32;k++){
    float4 ar4 = *(const float4*)&As[k][ty*4];
    float4 br4 = *(const float4*)&Bs[k][tx*4];
    float arr[4] = {ar4.x, ar4.y, ar4.z, ar4.w};
    float brr[4] = {br4.x, br4.y, br4.z, br4.w};
    #pragma unroll
    for(int i=0;i<4;i++)
      #pragma unroll
      for(int j=0;j<4;j++) acc[i][j] += arr[i]*brr[j];
  }
  #pragma unroll
  for(int i=0;i<4;i++){
    #pragma unroll
    for(int j=0;j<4;j++){
      int n = n0 + tx*4 + j;
      float v = acc[i][j] + bias[n];
      float sp = (v > 20.f) ? v : log1pf(expf(v));
      dt[(size_t)(m0+ty*4+i)*1024 + n] = sp;
    }
  }
}

// ---------------- selective scan (final state only) + gating -> yv[b][d] ----------------
__global__ __launch_bounds__(256) void k_scan(const float* __restrict__ dt,
    const float* __restrict__ u, const float* __restrict__ dbl,
    const float* __restrict__ alog, const float* __restrict__ Dp,
    const float* __restrict__ xz, float* __restrict__ yv){
  int b = blockIdx.x >> 6;             // 512 blocks: 8 b * 64 d-chunks
  int d0 = (blockIdx.x & 63) * 16;
  int tid = threadIdx.x;               // 256 = 16 d * 16 n
  int dd = tid >> 4, n = tid & 15;
  int d = d0 + dd;
  float Adn = -expf(alog[d*DSN + n]);
  __shared__ float sdt[64][16];
  __shared__ float su[64][16];
  __shared__ float sB[64][16];
  float h = 0.f;
  for(int t0=0; t0<LL; t0+=64){
    __syncthreads();
    #pragma unroll
    for(int r=0;r<4;r++){
      int idx = r*256 + tid;
      int tt = idx >> 4, di = idx & 15;
      int rowg = b*LL + t0 + tt;
      sdt[tt][di] = dt[(size_t)rowg*1024 + d0 + di];
      su [tt][di] = u [(size_t)rowg*1024 + d0 + di];
      sB [tt][di] = dbl[(size_t)rowg*64 + 32 + di];
    }
    __syncthreads();
    #pragma unroll 4
    for(int tt=0;tt<64;tt++){
      float dtv = sdt[tt][dd];
      float uv  = su[tt][dd];
      float Bv  = sB[tt][n];
      h = h * expf(dtv * Adn) + dtv * Bv * uv;
    }
  }
  float Cv = dbl[(size_t)(b*LL + LL-1)*64 + 48 + n];
  float p = h * Cv;
  p += __shfl_xor(p, 1);
  p += __shfl_xor(p, 2);
  p += __shfl_xor(p, 4);
  p += __shfl_xor(p, 8);
  if(n == 0){
    float ul = u[(size_t)(b*LL + LL-1)*1024 + d];
    float zl = xz[(size_t)(b*LL + LL-1)*2048 + 1024 + d];
    float sz = zl / (1.f + expf(-zl));
    yv[b*1024 + d] = (p + ul*Dp[d]) * sz;
  }
}

// ---------------- out_proj (last step only): xout[8][512] ----------------
__global__ __launch_bounds__(512) void k_outproj(const float* __restrict__ yv,
    const float* __restrict__ W, float* __restrict__ xout){
  int b = blockIdx.x;
  int j = threadIdx.x;
  __shared__ float sy[1024];
  sy[j] = yv[b*1024 + j];
  sy[j+512] = yv[b*1024 + 512 + j];
  __syncthreads();
  const float* w = W + (size_t)j*1024;
  float acc = 0.f;
  #pragma unroll 4
  for(int d2=0; d2<1024; d2+=4){
    float4 wv = *(const float4*)(w + d2);
    acc += sy[d2]*wv.x + sy[d2+1]*wv.y + sy[d2+2]*wv.z + sy[d2+3]*wv.w;
  }
  xout[b*512 + j] = acc;
}

// ---------------- head + denorm -> out[8][96][7] ----------------
__global__ __launch_bounds__(704) void k_head(const float* __restrict__ xout,
    const float* __restrict__ W, const float* __restrict__ hb,
    const float* __restrict__ mean, const float* __restrict__ stdv,
    float* __restrict__ out){
  int b = blockIdx.x;
  int o = threadIdx.x;
  __shared__ float sx[512];
  if(o < 512) sx[o] = xout[b*512 + o];
  __syncthreads();
  if(o < NOUTC){
    const float* w = W + (size_t)o*512;
    float acc = hb[o];
    #pragma unroll 4
    for(int j=0;j<512;j+=4){
      float4 wv = *(const float4*)(w + j);
      acc += sx[j]*wv.x + sx[j+1]*wv.y + sx[j+2]*wv.z + sx[j+3]*wv.w;
    }
    int c = o % 7;
    out[b*NOUTC + o] = acc * stdv[b*CIN + c] + mean[b*CIN + c];
  }
}

extern "C" void kernel_launch(void* const* d_in, const int* in_sizes, int n_in,
                              void* d_out, int out_size, void* d_ws, size_t ws_size,
                              hipStream_t stream) {
  const float* x_enc   = (const float*)d_in[0];
  const float* x_mark  = (const float*)d_in[1];
  const float* tconvw  = (const float*)d_in[4];
  const float* tempw   = (const float*)d_in[5];
  const float* inprojw = (const float*)d_in[6];
  const float* convw   = (const float*)d_in[7];
  const float* convb   = (const float*)d_in[8];
  const float* xprojw  = (const float*)d_in[9];
  const float* dtw     = (const float*)d_in[10];
  const float* dtb     = (const float*)d_in[11];
  const float* alog    = (const float*)d_in[12];
  const float* dpar    = (const float*)d_in[13];
  const float* outw    = (const float*)d_in[14];
  const float* headw   = (const float*)d_in[15];
  const float* headb   = (const float*)d_in[16];

  float* ws   = (float*)d_ws;
  float* mean = ws;                    // 56 (pad to 64)
  float* stdv = ws + 64;               // 56 (pad to 64)
  float* xn   = ws + 128;              // 28672
  float* x    = ws + 28800;            // 2,097,152
  float* xz   = x  + 2097152;          // 8,388,608
  float* u    = xz + 8388608;          // 4,194,304
  float* dbl  = u  + 4194304;          // 262,144
  float* dt   = dbl + 262144;          // 4,194,304
  float* yv   = dt + 4194304;          // 8192
  float* xout = yv + 8192;             // 4096
  float* out  = (float*)d_out;

  k_stats <<<56, 64, 0, stream>>>(x_enc, mean, stdv, xn);
  k_embed <<<512, 512, 0, stream>>>(xn, x_mark, tconvw, tempw, x);
  k_inproj<<<dim3(32, 64), 256, 0, stream>>>(x, inprojw, xz);
  k_dwconv<<<4096, 1024, 0, stream>>>(xz, convw, convb, u);
  k_xproj <<<dim3(1, 128), 256, 0, stream>>>(u, xprojw, dbl);
  k_dtproj<<<dim3(16, 64), 256, 0, stream>>>(dbl, dtw, dtb, dt);
  k_scan  <<<512, 256, 0, stream>>>(dt, u, dbl, alog, dpar, xz, yv);
  k_outproj<<<8, 512, 0, stream>>>(yv, outw, xout);
  k_head  <<<8, 704, 0, stream>>>(xout, headw, headb, mean, stdv, out);
}

// Round 2
// 193.858 us; speedup vs baseline: 1.9135x; 1.9135x over previous
//
#include <hip/hip_runtime.h>
#include <hip/hip_bf16.h>
#include <math.h>

#define BB 8
#define LL 512
#define CIN 7
#define MARKN 4
#define DM 512
#define DI 1024
#define DSN 16
#define NOUTC 672

typedef unsigned short ushortT;
typedef __attribute__((ext_vector_type(8))) short short8v;
typedef __attribute__((ext_vector_type(4))) float f32x4;

__device__ __forceinline__ float bf2f(ushortT u){ return __uint_as_float(((unsigned)u)<<16); }

// ---------------- stats: mean/std over L per (b,c), write normalized xn ----------------
__global__ __launch_bounds__(64) void k_stats(const float* __restrict__ xe,
    float* __restrict__ mean, float* __restrict__ stdv, float* __restrict__ xn){
  int bc = blockIdx.x;                 // 56
  int b = bc / CIN, c = bc % CIN;
  int t = threadIdx.x;                 // 64
  const float* base = xe + (b*LL)*CIN + c;
  float v[8]; float s = 0.f;
  #pragma unroll
  for(int i=0;i<8;i++){ v[i] = base[(t + i*64)*CIN]; s += v[i]; }
  #pragma unroll
  for(int o=32;o>=1;o>>=1) s += __shfl_down(s, o);
  float m = __shfl(s, 0) * (1.0f/LL);
  float vs = 0.f;
  #pragma unroll
  for(int i=0;i<8;i++){ float dv = v[i]-m; vs += dv*dv; }
  #pragma unroll
  for(int o=32;o>=1;o>>=1) vs += __shfl_down(vs, o);
  float var = __shfl(vs, 0) * (1.0f/LL);
  float sd = sqrtf(var + 1e-5f);
  float inv = 1.0f / sd;
  if(t == 0){ mean[bc] = m; stdv[bc] = sd; }
  float* xnb = xn + (b*LL)*CIN + c;
  #pragma unroll
  for(int i=0;i<8;i++) xnb[(t + i*64)*CIN] = (v[i]-m)*inv;
}

// ---------------- embedding: token conv (wrap pad) + temporal proj + PE -> bf16 x ----------------
__global__ __launch_bounds__(512) void k_embed(const float* __restrict__ xn,
    const float* __restrict__ xmark, const float* __restrict__ tw,
    const float* __restrict__ tpw, __hip_bfloat16* __restrict__ xo){
  __shared__ float sw[DM*21];          // token_conv_w staged (43KB)
  __shared__ float sxr[10][CIN];       // xn rows l0-1 .. l0+8 (wrap)
  __shared__ float smr[8][MARKN];
  int blk = blockIdx.x;                // 512 = 8 b * 64 chunks
  int b = blk >> 6;
  int l0 = (blk & 63) << 3;            // 8 l per block
  int tid = threadIdx.x;
  for(int i=tid; i<DM*21; i+=512) sw[i] = tw[i];
  if(tid < 70){
    int r = tid / CIN, c = tid % CIN;
    int ls = (l0 - 1 + r + LL) % LL;
    sxr[r][c] = xn[(b*LL + ls)*CIN + c];
  } else if(tid >= 128 && tid < 160){
    int i2 = tid - 128; int r = i2 >> 2, m = i2 & 3;
    smr[r][m] = xmark[(b*LL + l0 + r)*MARKN + m];
  }
  __syncthreads();
  int d = tid;
  float wv[21];
  #pragma unroll
  for(int i=0;i<21;i++) wv[i] = sw[d*21 + i];
  float tv[4];
  #pragma unroll
  for(int m=0;m<4;m++) tv[m] = tpw[d*MARKN + m];
  float divv = expf((float)(2*(d>>1)) * (-0.0179889460390159843f));
  bool isodd = (d & 1) != 0;
  #pragma unroll
  for(int ll=0; ll<8; ll++){
    float acc = 0.f;
    #pragma unroll
    for(int c=0;c<CIN;c++){
      #pragma unroll
      for(int k=0;k<3;k++) acc += sxr[ll+k][c] * wv[c*3+k];
    }
    #pragma unroll
    for(int m=0;m<4;m++) acc += smr[ll][m] * tv[m];
    float ang = (float)(l0+ll) * divv;
    acc += isodd ? cosf(ang) : sinf(ang);
    xo[(size_t)(b*LL + l0 + ll)*DM + d] = __float2bfloat16(acc);
  }
}

// ---------------- convert in_proj_w fp32 -> bf16 (all 2048 rows) ----------------
__global__ __launch_bounds__(256) void k_wconv(const float* __restrict__ w,
    ushortT* __restrict__ wbf){
  int i = (blockIdx.x*256 + threadIdx.x)*4;   // grid 1024 -> 1,048,576 elems
  float4 v = *(const float4*)(w + i);
  __hip_bfloat16 a0 = __float2bfloat16(v.x), a1 = __float2bfloat16(v.y);
  __hip_bfloat16 a2 = __float2bfloat16(v.z), a3 = __float2bfloat16(v.w);
  ushort4 pk;
  pk.x = *(ushortT*)&a0; pk.y = *(ushortT*)&a1; pk.z = *(ushortT*)&a2; pk.w = *(ushortT*)&a3;
  *(ushort4*)(wbf + i) = pk;
}

// ---------------- in_proj MFMA GEMM: xp[4096][1024] = Xbf[4096][512] @ Wbf[0:1024]^T ----------------
// 128x128 tile, BK=64, 4 waves (2x2), global_load_lds w16, XOR-swizzled LDS
__global__ __launch_bounds__(256) void k_inproj_mfma(const ushortT* __restrict__ A,
    const ushortT* __restrict__ Bw, float* __restrict__ C){
  __shared__ ushortT Asl[128*64];
  __shared__ ushortT Bsl[128*64];
  int tid = threadIdx.x;
  int w = tid >> 6, l = tid & 63;
  int m0 = blockIdx.y * 128, n0 = blockIdx.x * 128;
  int wr = w >> 1, wc = w & 1;
  f32x4 acc[4][4] = {};
  int srow = l >> 3;                    // row within 8-row staging group
  int scolswz = ((l & 7) * 16) ^ (srow << 4);  // pre-swizzled source byte col
  for(int kt = 0; kt < 8; ++kt){
    __syncthreads();
    #pragma unroll
    for(int i=0;i<4;i++){
      int r0 = w*32 + i*8;
      int r = r0 + srow;
      const ushortT* gA = A + (size_t)(m0 + r)*512 + kt*64 + (scolswz>>1);
      const ushortT* gB = Bw + (size_t)(n0 + r)*512 + kt*64 + (scolswz>>1);
      __builtin_amdgcn_global_load_lds(
        (const __attribute__((address_space(1))) unsigned int*)(const void*)gA,
        (__attribute__((address_space(3))) unsigned int*)(void*)(Asl + r0*64), 16, 0, 0);
      __builtin_amdgcn_global_load_lds(
        (const __attribute__((address_space(1))) unsigned int*)(const void*)gB,
        (__attribute__((address_space(3))) unsigned int*)(void*)(Bsl + r0*64), 16, 0, 0);
    }
    __syncthreads();
    #pragma unroll
    for(int kk=0;kk<2;kk++){
      short8v af[4], bfr[4];
      int cb = kk*64 + (l>>4)*16;       // byte col of this lane's fragment
      #pragma unroll
      for(int mf=0;mf<4;mf++){
        int ar = wr*64 + mf*16 + (l&15);
        af[mf] = *(const short8v*)(Asl + ar*64 + ((cb ^ ((ar&7)<<4))>>1));
      }
      #pragma unroll
      for(int nf=0;nf<4;nf++){
        int br = wc*64 + nf*16 + (l&15);
        bfr[nf] = *(const short8v*)(Bsl + br*64 + ((cb ^ ((br&7)<<4))>>1));
      }
      #pragma unroll
      for(int mf=0;mf<4;mf++)
        #pragma unroll
        for(int nf=0;nf<4;nf++)
          acc[mf][nf] = __builtin_amdgcn_mfma_f32_16x16x32_bf16(af[mf], bfr[nf], acc[mf][nf], 0, 0, 0);
    }
  }
  #pragma unroll
  for(int mf=0;mf<4;mf++){
    int rbase = m0 + wr*64 + mf*16 + (l>>4)*4;
    #pragma unroll
    for(int nf=0;nf<4;nf++){
      int col = n0 + wc*64 + nf*16 + (l&15);
      #pragma unroll
      for(int r=0;r<4;r++)
        C[(size_t)(rbase+r)*1024 + col] = acc[mf][nf][r];
    }
  }
}

// ---------------- z_last[8][1024] = x[b,511,:] @ W[1024+d]^T ----------------
__global__ __launch_bounds__(256) void k_zlast(const ushortT* __restrict__ xbf,
    const ushortT* __restrict__ wbf, float* __restrict__ zl){
  int g = blockIdx.x*256 + threadIdx.x;  // grid 32 -> 8192 threads
  int d = g >> 3, b = g & 7;
  const ushortT* xr = xbf + (size_t)(b*LL + LL-1)*512;
  const ushortT* wr = wbf + (size_t)(1024 + d)*512;
  float acc = 0.f;
  for(int k=0;k<512;k+=4){
    ushort4 xv = *(const ushort4*)(xr + k);
    ushort4 wv = *(const ushort4*)(wr + k);
    acc += bf2f(xv.x)*bf2f(wv.x) + bf2f(xv.y)*bf2f(wv.y)
         + bf2f(xv.z)*bf2f(wv.z) + bf2f(xv.w)*bf2f(wv.w);
  }
  zl[b*1024 + d] = acc;
}

// ---------------- causal depthwise conv (D_CONV=4) + silu -> u ----------------
__global__ __launch_bounds__(1024) void k_dwconv(const float* __restrict__ xp,
    const float* __restrict__ cw, const float* __restrict__ cb, float* __restrict__ u){
  int bl = blockIdx.x;                 // 4096
  int b = bl >> 9, l = bl & 511;
  int d = threadIdx.x;                 // 1024
  const float4 w4 = *(const float4*)(cw + d*4);
  const float* base = xp + (size_t)(b*LL)*1024 + d;
  float acc = cb[d];
  if(l >= 3) acc += base[(size_t)(l-3)*1024] * w4.x;
  if(l >= 2) acc += base[(size_t)(l-2)*1024] * w4.y;
  if(l >= 1) acc += base[(size_t)(l-1)*1024] * w4.z;
  acc += base[(size_t)l*1024] * w4.w;
  float s = acc / (1.f + expf(-acc));
  u[(size_t)bl*1024 + d] = s;
}

// ---------------- x_proj GEMM: dbl[4096][64] = u[4096][1024] @ W[64][1024]^T ----------------
__global__ __launch_bounds__(256) void k_xproj(const float* __restrict__ A,
    const float* __restrict__ W, float* __restrict__ C){
  __shared__ __align__(16) float As[16][36];
  __shared__ __align__(16) float Bs[16][68];
  int tid = threadIdx.x;
  int m0 = blockIdx.y * 32;            // 128 blocks
  int tx = tid & 15, ty = tid >> 4;
  int arow = tid >> 3, ak = (tid & 7) * 2;
  int brow = tid >> 2, bk = (tid & 3) * 4;
  float acc[2][4] = {};
  for(int k0=0;k0<1024;k0+=16){
    float2 av = *(const float2*)(A + (size_t)(m0+arow)*1024 + k0 + ak);
    float4 bv = *(const float4*)(W + (size_t)brow*1024 + k0 + bk);
    As[ak][arow]=av.x; As[ak+1][arow]=av.y;
    Bs[bk+0][brow]=bv.x; Bs[bk+1][brow]=bv.y; Bs[bk+2][brow]=bv.z; Bs[bk+3][brow]=bv.w;
    __syncthreads();
    #pragma unroll
    for(int k=0;k<16;k++){
      float a0 = As[k][ty*2], a1 = As[k][ty*2+1];
      float4 br4 = *(const float4*)&Bs[k][tx*4];
      float brr[4] = {br4.x, br4.y, br4.z, br4.w};
      #pragma unroll
      for(int j=0;j<4;j++){ acc[0][j] += a0*brr[j]; acc[1][j] += a1*brr[j]; }
    }
    __syncthreads();
  }
  #pragma unroll
  for(int i=0;i<2;i++){
    float4 cv = make_float4(acc[i][0],acc[i][1],acc[i][2],acc[i][3]);
    *(float4*)(C + (size_t)(m0+ty*2+i)*64 + tx*4) = cv;
  }
}

// ---------------- dt_proj + softplus: dt[4096][1024] ----------------
__global__ __launch_bounds__(256) void k_dtproj(const float* __restrict__ dbl,
    const float* __restrict__ W, const float* __restrict__ bias, float* __restrict__ dt){
  __shared__ __align__(16) float As[32][68];
  __shared__ __align__(16) float Bs[32][68];
  int tid = threadIdx.x;
  int n0 = blockIdx.x * 64, m0 = blockIdx.y * 64;
  int tx = tid & 15, ty = tid >> 4;
  int row = tid >> 2, lk = (tid & 3) * 8;
  {
    float4 a0 = *(const float4*)(dbl + (size_t)(m0+row)*64 + lk);
    float4 a1 = *(const float4*)(dbl + (size_t)(m0+row)*64 + lk + 4);
    As[lk+0][row]=a0.x; As[lk+1][row]=a0.y; As[lk+2][row]=a0.z; As[lk+3][row]=a0.w;
    As[lk+4][row]=a1.x; As[lk+5][row]=a1.y; As[lk+6][row]=a1.z; As[lk+7][row]=a1.w;
    float4 b0 = *(const float4*)(W + (size_t)(n0+row)*32 + lk);
    float4 b1 = *(const float4*)(W + (size_t)(n0+row)*32 + lk + 4);
    Bs[lk+0][row]=b0.x; Bs[lk+1][row]=b0.y; Bs[lk+2][row]=b0.z; Bs[lk+3][row]=b0.w;
    Bs[lk+4][row]=b1.x; Bs[lk+5][row]=b1.y; Bs[lk+6][row]=b1.z; Bs[lk+7][row]=b1.w;
  }
  __syncthreads();
  float acc[4][4] = {};
  #pragma unroll
  for(int k=0;k<32;k++){
    float4 ar4 = *(const float4*)&As[k][ty*4];
    float4 br4 = *(const float4*)&Bs[k][tx*4];
    float arr[4] = {ar4.x, ar4.y, ar4.z, ar4.w};
    float brr[4] = {br4.x, br4.y, br4.z, br4.w};
    #pragma unroll
    for(int i=0;i<4;i++)
      #pragma unroll
      for(int j=0;j<4;j++) acc[i][j] += arr[i]*brr[j];
  }
  #pragma unroll
  for(int i=0;i<4;i++){
    #pragma unroll
    for(int j=0;j<4;j++){
      int n = n0 + tx*4 + j;
      float v = acc[i][j] + bias[n];
      float sp = (v > 20.f) ? v : log1pf(expf(v));
      dt[(size_t)(m0+ty*4+i)*1024 + n] = sp;
    }
  }
}

// ---------------- selective scan (final state only) + gating -> yv[b][d] ----------------
__global__ __launch_bounds__(256) void k_scan(const float* __restrict__ dt,
    const float* __restrict__ u, const float* __restrict__ dbl,
    const float* __restrict__ alog, const float* __restrict__ Dp,
    const float* __restrict__ zlast, float* __restrict__ yv){
  int b = blockIdx.x >> 6;             // 512 blocks: 8 b * 64 d-chunks
  int d0 = (blockIdx.x & 63) * 16;
  int tid = threadIdx.x;               // 256 = 16 d * 16 n
  int dd = tid >> 4, n = tid & 15;
  int d = d0 + dd;
  float Adn = -expf(alog[d*DSN + n]);
  __shared__ float sdt[64][16];
  __shared__ float su[64][16];
  __shared__ float sB[64][16];
  float h = 0.f;
  for(int t0=0; t0<LL; t0+=64){
    __syncthreads();
    #pragma unroll
    for(int r=0;r<4;r++){
      int idx = r*256 + tid;
      int tt = idx >> 4, di = idx & 15;
      int rowg = b*LL + t0 + tt;
      sdt[tt][di] = dt[(size_t)rowg*1024 + d0 + di];
      su [tt][di] = u [(size_t)rowg*1024 + d0 + di];
      sB [tt][di] = dbl[(size_t)rowg*64 + 32 + di];
    }
    __syncthreads();
    #pragma unroll 4
    for(int tt=0;tt<64;tt++){
      float dtv = sdt[tt][dd];
      float uv  = su[tt][dd];
      float Bv  = sB[tt][n];
      h = h * expf(dtv * Adn) + dtv * Bv * uv;
    }
  }
  float Cv = dbl[(size_t)(b*LL + LL-1)*64 + 48 + n];
  float p = h * Cv;
  p += __shfl_xor(p, 1);
  p += __shfl_xor(p, 2);
  p += __shfl_xor(p, 4);
  p += __shfl_xor(p, 8);
  if(n == 0){
    float ul = u[(size_t)(b*LL + LL-1)*1024 + d];
    float zl = zlast[b*1024 + d];
    float sz = zl / (1.f + expf(-zl));
    yv[b*1024 + d] = (p + ul*Dp[d]) * sz;
  }
}

// ---------------- out_proj (last step only): xout[8][512], weight rows read once ----------------
__global__ __launch_bounds__(256) void k_outproj(const float* __restrict__ yv,
    const float* __restrict__ W, float* __restrict__ xout){
  int tid = threadIdx.x;
  int j = blockIdx.x*8 + (tid>>5);     // 64 blocks -> 512 outputs
  int ks = tid & 31;
  float a[8] = {};
  #pragma unroll
  for(int t=0;t<8;t++){
    int k = ks*4 + t*128;
    float4 wv = *(const float4*)(W + (size_t)j*1024 + k);
    #pragma unroll
    for(int b=0;b<8;b++){
      float4 xv = *(const float4*)(yv + b*1024 + k);
      a[b] += xv.x*wv.x + xv.y*wv.y + xv.z*wv.z + xv.w*wv.w;
    }
  }
  #pragma unroll
  for(int b=0;b<8;b++){
    #pragma unroll
    for(int o=16;o>=1;o>>=1) a[b] += __shfl_xor(a[b], o);
  }
  if(ks==0){
    #pragma unroll
    for(int b=0;b<8;b++) xout[b*512 + j] = a[b];
  }
}

// ---------------- head + denorm -> out[8][96][7], weight rows read once ----------------
__global__ __launch_bounds__(256) void k_head(const float* __restrict__ xout,
    const float* __restrict__ W, const float* __restrict__ hb,
    const float* __restrict__ mean, const float* __restrict__ stdv,
    float* __restrict__ out){
  int tid = threadIdx.x;
  int o = blockIdx.x*8 + (tid>>5);     // 84 blocks -> 672 outputs
  int ks = tid & 31;
  float a[8] = {};
  #pragma unroll
  for(int t=0;t<4;t++){
    int k = ks*4 + t*128;
    float4 wv = *(const float4*)(W + (size_t)o*512 + k);
    #pragma unroll
    for(int b=0;b<8;b++){
      float4 xv = *(const float4*)(xout + b*512 + k);
      a[b] += xv.x*wv.x + xv.y*wv.y + xv.z*wv.z + xv.w*wv.w;
    }
  }
  #pragma unroll
  for(int b=0;b<8;b++){
    #pragma unroll
    for(int oo=16;oo>=1;oo>>=1) a[b] += __shfl_xor(a[b], oo);
  }
  if(ks==0){
    int c = o % 7;
    #pragma unroll
    for(int b=0;b<8;b++){
      float v = a[b] + hb[o];
      out[b*NOUTC + o] = v * stdv[b*CIN + c] + mean[b*CIN + c];
    }
  }
}

extern "C" void kernel_launch(void* const* d_in, const int* in_sizes, int n_in,
                              void* d_out, int out_size, void* d_ws, size_t ws_size,
                              hipStream_t stream) {
  const float* x_enc   = (const float*)d_in[0];
  const float* x_mark  = (const float*)d_in[1];
  const float* tconvw  = (const float*)d_in[4];
  const float* tempw   = (const float*)d_in[5];
  const float* inprojw = (const float*)d_in[6];
  const float* convw   = (const float*)d_in[7];
  const float* convb   = (const float*)d_in[8];
  const float* xprojw  = (const float*)d_in[9];
  const float* dtw     = (const float*)d_in[10];
  const float* dtb     = (const float*)d_in[11];
  const float* alog    = (const float*)d_in[12];
  const float* dpar    = (const float*)d_in[13];
  const float* outw    = (const float*)d_in[14];
  const float* headw   = (const float*)d_in[15];
  const float* headb   = (const float*)d_in[16];

  float* ws    = (float*)d_ws;
  float* mean  = ws;                          // 64
  float* stdv  = ws + 64;                     // 64
  float* xn    = ws + 128;                    // 28672 -> 28800
  ushortT* xbf = (ushortT*)(ws + 28800);      // 4096*512 u16 = 1,048,576 f -> 1,077,376
  ushortT* wbf = (ushortT*)(ws + 1077376);    // 2048*512 u16 = 524,288 f -> 1,601,664
  float* xp    = ws + 1601664;                // 4,194,304 -> 5,795,968
  float* zlast = ws + 5795968;                // 8192 -> 5,804,160
  float* u     = ws + 5804160;                // 4,194,304 -> 9,998,464
  float* dbl   = ws + 9998464;                // 262,144 -> 10,260,608
  float* dt    = ws + 10260608;               // 4,194,304 -> 14,454,912
  float* yv    = ws + 14454912;               // 8192 -> 14,463,104
  float* xout  = ws + 14463104;               // 4096 -> 14,467,200
  float* out   = (float*)d_out;

  k_stats <<<56, 64, 0, stream>>>(x_enc, mean, stdv, xn);
  k_embed <<<512, 512, 0, stream>>>(xn, x_mark, tconvw, tempw, (__hip_bfloat16*)xbf);
  k_wconv <<<1024, 256, 0, stream>>>(inprojw, wbf);
  k_inproj_mfma<<<dim3(8, 32), 256, 0, stream>>>(xbf, wbf, xp);
  k_zlast <<<32, 256, 0, stream>>>(xbf, wbf, zlast);
  k_dwconv<<<4096, 1024, 0, stream>>>(xp, convw, convb, u);
  k_xproj <<<dim3(1, 128), 256, 0, stream>>>(u, xprojw, dbl);
  k_dtproj<<<dim3(16, 64), 256, 0, stream>>>(dbl, dtw, dtb, dt);
  k_scan  <<<512, 256, 0, stream>>>(dt, u, dbl, alog, dpar, zlast, yv);
  k_outproj<<<64, 256, 0, stream>>>(yv, outw, xout);
  k_head  <<<84, 256, 0, stream>>>(xout, headw, headb, mean, stdv, out);
}

// Round 3
// 168.836 us; speedup vs baseline: 2.1971x; 1.1482x over previous
//
#include <hip/hip_runtime.h>
#include <hip/hip_bf16.h>
#include <math.h>

#define BB 8
#define LL 512
#define CIN 7
#define MARKN 4
#define DM 512
#define DI 1024
#define DSN 16
#define NOUTC 672

typedef unsigned short ushortT;
typedef __attribute__((ext_vector_type(8))) short short8v;
typedef __attribute__((ext_vector_type(4))) float f32x4;

__device__ __forceinline__ float bf2f(ushortT u){ return __uint_as_float(((unsigned)u)<<16); }

// ---------------- stats: mean/std over L per (b,c), write normalized xn ----------------
__global__ __launch_bounds__(64) void k_stats(const float* __restrict__ xe,
    float* __restrict__ mean, float* __restrict__ stdv, float* __restrict__ xn){
  int bc = blockIdx.x;                 // 56
  int b = bc / CIN, c = bc % CIN;
  int t = threadIdx.x;                 // 64
  const float* base = xe + (b*LL)*CIN + c;
  float v[8]; float s = 0.f;
  #pragma unroll
  for(int i=0;i<8;i++){ v[i] = base[(t + i*64)*CIN]; s += v[i]; }
  #pragma unroll
  for(int o=32;o>=1;o>>=1) s += __shfl_down(s, o);
  float m = __shfl(s, 0) * (1.0f/LL);
  float vs = 0.f;
  #pragma unroll
  for(int i=0;i<8;i++){ float dv = v[i]-m; vs += dv*dv; }
  #pragma unroll
  for(int o=32;o>=1;o>>=1) vs += __shfl_down(vs, o);
  float var = __shfl(vs, 0) * (1.0f/LL);
  float sd = sqrtf(var + 1e-5f);
  float inv = 1.0f / sd;
  if(t == 0){ mean[bc] = m; stdv[bc] = sd; }
  float* xnb = xn + (b*LL)*CIN + c;
  #pragma unroll
  for(int i=0;i<8;i++) xnb[(t + i*64)*CIN] = (v[i]-m)*inv;
}

// ---------------- embedding: token conv (wrap pad) + temporal proj + PE -> bf16 x ----------------
__global__ __launch_bounds__(512) void k_embed(const float* __restrict__ xn,
    const float* __restrict__ xmark, const float* __restrict__ tw,
    const float* __restrict__ tpw, __hip_bfloat16* __restrict__ xo){
  __shared__ float sw[DM*21];          // token_conv_w staged (43KB)
  __shared__ float sxr[10][CIN];       // xn rows l0-1 .. l0+8 (wrap)
  __shared__ float smr[8][MARKN];
  int blk = blockIdx.x;                // 512 = 8 b * 64 chunks
  int b = blk >> 6;
  int l0 = (blk & 63) << 3;            // 8 l per block
  int tid = threadIdx.x;
  for(int i=tid; i<DM*21; i+=512) sw[i] = tw[i];
  if(tid < 70){
    int r = tid / CIN, c = tid % CIN;
    int ls = (l0 - 1 + r + LL) % LL;
    sxr[r][c] = xn[(b*LL + ls)*CIN + c];
  } else if(tid >= 128 && tid < 160){
    int i2 = tid - 128; int r = i2 >> 2, m = i2 & 3;
    smr[r][m] = xmark[(b*LL + l0 + r)*MARKN + m];
  }
  __syncthreads();
  int d = tid;
  float wv[21];
  #pragma unroll
  for(int i=0;i<21;i++) wv[i] = sw[d*21 + i];
  float tv[4];
  #pragma unroll
  for(int m=0;m<4;m++) tv[m] = tpw[d*MARKN + m];
  float divv = expf((float)(2*(d>>1)) * (-0.0179889460390159843f));
  bool isodd = (d & 1) != 0;
  #pragma unroll
  for(int ll=0; ll<8; ll++){
    float acc = 0.f;
    #pragma unroll
    for(int c=0;c<CIN;c++){
      #pragma unroll
      for(int k=0;k<3;k++) acc += sxr[ll+k][c] * wv[c*3+k];
    }
    #pragma unroll
    for(int m=0;m<4;m++) acc += smr[ll][m] * tv[m];
    float ang = (float)(l0+ll) * divv;
    acc += isodd ? cosf(ang) : sinf(ang);
    xo[(size_t)(b*LL + l0 + ll)*DM + d] = __float2bfloat16(acc);
  }
}

// ---------------- convert in_proj_w fp32 -> bf16 (all 2048 rows) ----------------
__global__ __launch_bounds__(256) void k_wconv(const float* __restrict__ w,
    ushortT* __restrict__ wbf){
  int i = (blockIdx.x*256 + threadIdx.x)*4;   // grid 1024 -> 1,048,576 elems
  float4 v = *(const float4*)(w + i);
  __hip_bfloat16 a0 = __float2bfloat16(v.x), a1 = __float2bfloat16(v.y);
  __hip_bfloat16 a2 = __float2bfloat16(v.z), a3 = __float2bfloat16(v.w);
  ushort4 pk;
  pk.x = *(ushortT*)&a0; pk.y = *(ushortT*)&a1; pk.z = *(ushortT*)&a2; pk.w = *(ushortT*)&a3;
  *(ushort4*)(wbf + i) = pk;
}

// ---------------- convert x_proj_w fp32 -> bf16 (64 x 1024) ----------------
__global__ __launch_bounds__(256) void k_wconv2(const float* __restrict__ w,
    ushortT* __restrict__ wbf){
  int i = (blockIdx.x*256 + threadIdx.x)*4;   // grid 64 -> 65,536 elems
  float4 v = *(const float4*)(w + i);
  __hip_bfloat16 a0 = __float2bfloat16(v.x), a1 = __float2bfloat16(v.y);
  __hip_bfloat16 a2 = __float2bfloat16(v.z), a3 = __float2bfloat16(v.w);
  ushort4 pk;
  pk.x = *(ushortT*)&a0; pk.y = *(ushortT*)&a1; pk.z = *(ushortT*)&a2; pk.w = *(ushortT*)&a3;
  *(ushort4*)(wbf + i) = pk;
}

// ---------------- in_proj MFMA GEMM: xp[4096][1024] = Xbf[4096][512] @ Wbf[0:1024]^T ----------------
// 128x128 tile, BK=64, 4 waves (2x2), global_load_lds w16, XOR-swizzled LDS
__global__ __launch_bounds__(256) void k_inproj_mfma(const ushortT* __restrict__ A,
    const ushortT* __restrict__ Bw, float* __restrict__ C){
  __shared__ ushortT Asl[128*64];
  __shared__ ushortT Bsl[128*64];
  int tid = threadIdx.x;
  int w = tid >> 6, l = tid & 63;
  int m0 = blockIdx.y * 128, n0 = blockIdx.x * 128;
  int wr = w >> 1, wc = w & 1;
  f32x4 acc[4][4] = {};
  int srow = l >> 3;                    // row within 8-row staging group
  int scolswz = ((l & 7) * 16) ^ (srow << 4);  // pre-swizzled source byte col
  for(int kt = 0; kt < 8; ++kt){
    __syncthreads();
    #pragma unroll
    for(int i=0;i<4;i++){
      int r0 = w*32 + i*8;
      int r = r0 + srow;
      const ushortT* gA = A + (size_t)(m0 + r)*512 + kt*64 + (scolswz>>1);
      const ushortT* gB = Bw + (size_t)(n0 + r)*512 + kt*64 + (scolswz>>1);
      __builtin_amdgcn_global_load_lds(
        (const __attribute__((address_space(1))) unsigned int*)(const void*)gA,
        (__attribute__((address_space(3))) unsigned int*)(void*)(Asl + r0*64), 16, 0, 0);
      __builtin_amdgcn_global_load_lds(
        (const __attribute__((address_space(1))) unsigned int*)(const void*)gB,
        (__attribute__((address_space(3))) unsigned int*)(void*)(Bsl + r0*64), 16, 0, 0);
    }
    __syncthreads();
    #pragma unroll
    for(int kk=0;kk<2;kk++){
      short8v af[4], bfr[4];
      int cb = kk*64 + (l>>4)*16;       // byte col of this lane's fragment
      #pragma unroll
      for(int mf=0;mf<4;mf++){
        int ar = wr*64 + mf*16 + (l&15);
        af[mf] = *(const short8v*)(Asl + ar*64 + ((cb ^ ((ar&7)<<4))>>1));
      }
      #pragma unroll
      for(int nf=0;nf<4;nf++){
        int br = wc*64 + nf*16 + (l&15);
        bfr[nf] = *(const short8v*)(Bsl + br*64 + ((cb ^ ((br&7)<<4))>>1));
      }
      #pragma unroll
      for(int mf=0;mf<4;mf++)
        #pragma unroll
        for(int nf=0;nf<4;nf++)
          acc[mf][nf] = __builtin_amdgcn_mfma_f32_16x16x32_bf16(af[mf], bfr[nf], acc[mf][nf], 0, 0, 0);
    }
  }
  #pragma unroll
  for(int mf=0;mf<4;mf++){
    int rbase = m0 + wr*64 + mf*16 + (l>>4)*4;
    #pragma unroll
    for(int nf=0;nf<4;nf++){
      int col = n0 + wc*64 + nf*16 + (l&15);
      #pragma unroll
      for(int r=0;r<4;r++)
        C[(size_t)(rbase+r)*1024 + col] = acc[mf][nf][r];
    }
  }
}

// ---------------- z_last[8][1024] = x[b,511,:] @ W[1024+d]^T ----------------
__global__ __launch_bounds__(256) void k_zlast(const ushortT* __restrict__ xbf,
    const ushortT* __restrict__ wbf, float* __restrict__ zl){
  int g = blockIdx.x*256 + threadIdx.x;  // grid 32 -> 8192 threads
  int d = g >> 3, b = g & 7;
  const ushortT* xr = xbf + (size_t)(b*LL + LL-1)*512;
  const ushortT* wr = wbf + (size_t)(1024 + d)*512;
  float acc = 0.f;
  for(int k=0;k<512;k+=4){
    ushort4 xv = *(const ushort4*)(xr + k);
    ushort4 wv = *(const ushort4*)(wr + k);
    acc += bf2f(xv.x)*bf2f(wv.x) + bf2f(xv.y)*bf2f(wv.y)
         + bf2f(xv.z)*bf2f(wv.z) + bf2f(xv.w)*bf2f(wv.w);
  }
  zl[b*1024 + d] = acc;
}

// ---------------- causal depthwise conv (D_CONV=4) + silu -> u (fp32 + bf16) ----------------
__global__ __launch_bounds__(1024) void k_dwconv(const float* __restrict__ xp,
    const float* __restrict__ cw, const float* __restrict__ cb,
    float* __restrict__ u, ushortT* __restrict__ ubf){
  int bl = blockIdx.x;                 // 4096
  int b = bl >> 9, l = bl & 511;
  int d = threadIdx.x;                 // 1024
  const float4 w4 = *(const float4*)(cw + d*4);
  const float* base = xp + (size_t)(b*LL)*1024 + d;
  float acc = cb[d];
  if(l >= 3) acc += base[(size_t)(l-3)*1024] * w4.x;
  if(l >= 2) acc += base[(size_t)(l-2)*1024] * w4.y;
  if(l >= 1) acc += base[(size_t)(l-1)*1024] * w4.z;
  acc += base[(size_t)l*1024] * w4.w;
  float s = acc / (1.f + expf(-acc));
  u[(size_t)bl*1024 + d] = s;
  __hip_bfloat16 h = __float2bfloat16(s);
  ubf[(size_t)bl*1024 + d] = *(ushortT*)&h;
}

// ---------------- x_proj MFMA GEMM: dbl[4096][64] = ubf[4096][1024] @ Wbf[64][1024]^T ----------------
// 64x64 tile, BK=64, 4 waves (each 16 rows x 64 cols), 2-phase double-buffered LDS
__global__ __launch_bounds__(256) void k_xproj_mfma(const ushortT* __restrict__ A,
    const ushortT* __restrict__ Bw, float* __restrict__ C){
  __shared__ ushortT Asl[2][64*64];
  __shared__ ushortT Bsl[2][64*64];
  int tid = threadIdx.x;
  int w = tid >> 6, l = tid & 63;
  int m0 = blockIdx.x * 64;
  f32x4 acc[4] = {};
  int srow = l >> 3;
  int scol = ((l & 7) * 16) ^ (srow << 4);   // pre-swizzled source byte col

#define XP_STAGE(bufi, kt) do{ \
    _Pragma("unroll") \
    for(int i=0;i<2;i++){ \
      int r0 = w*16 + i*8; \
      int r = r0 + srow; \
      const ushortT* gA = A + (size_t)(m0 + r)*1024 + (kt)*64 + (scol>>1); \
      const ushortT* gB = Bw + (size_t)r*1024 + (kt)*64 + (scol>>1); \
      __builtin_amdgcn_global_load_lds( \
        (const __attribute__((address_space(1))) unsigned int*)(const void*)gA, \
        (__attribute__((address_space(3))) unsigned int*)(void*)(Asl[bufi] + r0*64), 16, 0, 0); \
      __builtin_amdgcn_global_load_lds( \
        (const __attribute__((address_space(1))) unsigned int*)(const void*)gB, \
        (__attribute__((address_space(3))) unsigned int*)(void*)(Bsl[bufi] + r0*64), 16, 0, 0); \
    } }while(0)

  XP_STAGE(0, 0);
  __syncthreads();                      // vmcnt(0) drain before first compute
  int cur = 0;
  for(int kt = 0; kt < 16; ++kt){
    if(kt < 15) XP_STAGE(cur^1, kt+1);  // prefetch next tile, overlaps compute
    #pragma unroll
    for(int kk=0;kk<2;kk++){
      int cb = kk*64 + (l>>4)*16;
      int ar = w*16 + (l&15);
      short8v af = *(const short8v*)(Asl[cur] + ar*64 + ((cb ^ ((ar&7)<<4))>>1));
      #pragma unroll
      for(int nf=0;nf<4;nf++){
        int br = nf*16 + (l&15);
        short8v bfv = *(const short8v*)(Bsl[cur] + br*64 + ((cb ^ ((br&7)<<4))>>1));
        acc[nf] = __builtin_amdgcn_mfma_f32_16x16x32_bf16(af, bfv, acc[nf], 0, 0, 0);
      }
    }
    __syncthreads();
    cur ^= 1;
  }
#undef XP_STAGE
  int rbase = m0 + w*16 + (l>>4)*4;
  #pragma unroll
  for(int nf=0;nf<4;nf++){
    int col = nf*16 + (l&15);
    #pragma unroll
    for(int r=0;r<4;r++)
      C[(size_t)(rbase+r)*64 + col] = acc[nf][r];
  }
}

// ---------------- dt_proj + softplus: dt[4096][1024] ----------------
__global__ __launch_bounds__(256) void k_dtproj(const float* __restrict__ dbl,
    const float* __restrict__ W, const float* __restrict__ bias, float* __restrict__ dt){
  __shared__ __align__(16) float As[32][68];
  __shared__ __align__(16) float Bs[32][68];
  int tid = threadIdx.x;
  int n0 = blockIdx.x * 64, m0 = blockIdx.y * 64;
  int tx = tid & 15, ty = tid >> 4;
  int row = tid >> 2, lk = (tid & 3) * 8;
  {
    float4 a0 = *(const float4*)(dbl + (size_t)(m0+row)*64 + lk);
    float4 a1 = *(const float4*)(dbl + (size_t)(m0+row)*64 + lk + 4);
    As[lk+0][row]=a0.x; As[lk+1][row]=a0.y; As[lk+2][row]=a0.z; As[lk+3][row]=a0.w;
    As[lk+4][row]=a1.x; As[lk+5][row]=a1.y; As[lk+6][row]=a1.z; As[lk+7][row]=a1.w;
    float4 b0 = *(const float4*)(W + (size_t)(n0+row)*32 + lk);
    float4 b1 = *(const float4*)(W + (size_t)(n0+row)*32 + lk + 4);
    Bs[lk+0][row]=b0.x; Bs[lk+1][row]=b0.y; Bs[lk+2][row]=b0.z; Bs[lk+3][row]=b0.w;
    Bs[lk+4][row]=b1.x; Bs[lk+5][row]=b1.y; Bs[lk+6][row]=b1.z; Bs[lk+7][row]=b1.w;
  }
  __syncthreads();
  float acc[4][4] = {};
  #pragma unroll
  for(int k=0;k<32;k++){
    float4 ar4 = *(const float4*)&As[k][ty*4];
    float4 br4 = *(const float4*)&Bs[k][tx*4];
    float arr[4] = {ar4.x, ar4.y, ar4.z, ar4.w};
    float brr[4] = {br4.x, br4.y, br4.z, br4.w};
    #pragma unroll
    for(int i=0;i<4;i++)
      #pragma unroll
      for(int j=0;j<4;j++) acc[i][j] += arr[i]*brr[j];
  }
  #pragma unroll
  for(int i=0;i<4;i++){
    #pragma unroll
    for(int j=0;j<4;j++){
      int n = n0 + tx*4 + j;
      float v = acc[i][j] + bias[n];
      float sp = (v > 20.f) ? v : log1pf(expf(v));
      dt[(size_t)(m0+ty*4+i)*1024 + n] = sp;
    }
  }
}

// ---------------- selective scan (final state only) + gating -> yv[b][d] ----------------
__global__ __launch_bounds__(256) void k_scan(const float* __restrict__ dt,
    const float* __restrict__ u, const float* __restrict__ dbl,
    const float* __restrict__ alog, const float* __restrict__ Dp,
    const float* __restrict__ zlast, float* __restrict__ yv){
  int b = blockIdx.x >> 6;             // 512 blocks: 8 b * 64 d-chunks
  int d0 = (blockIdx.x & 63) * 16;
  int tid = threadIdx.x;               // 256 = 16 d * 16 n
  int dd = tid >> 4, n = tid & 15;
  int d = d0 + dd;
  float Adn = -expf(alog[d*DSN + n]);
  __shared__ float sdt[64][16];
  __shared__ float su[64][16];
  __shared__ float sB[64][16];
  float h = 0.f;
  for(int t0=0; t0<LL; t0+=64){
    __syncthreads();
    #pragma unroll
    for(int r=0;r<4;r++){
      int idx = r*256 + tid;
      int tt = idx >> 4, di = idx & 15;
      int rowg = b*LL + t0 + tt;
      sdt[tt][di] = dt[(size_t)rowg*1024 + d0 + di];
      su [tt][di] = u [(size_t)rowg*1024 + d0 + di];
      sB [tt][di] = dbl[(size_t)rowg*64 + 32 + di];
    }
    __syncthreads();
    #pragma unroll 4
    for(int tt=0;tt<64;tt++){
      float dtv = sdt[tt][dd];
      float uv  = su[tt][dd];
      float Bv  = sB[tt][n];
      h = h * expf(dtv * Adn) + dtv * Bv * uv;
    }
  }
  float Cv = dbl[(size_t)(b*LL + LL-1)*64 + 48 + n];
  float p = h * Cv;
  p += __shfl_xor(p, 1);
  p += __shfl_xor(p, 2);
  p += __shfl_xor(p, 4);
  p += __shfl_xor(p, 8);
  if(n == 0){
    float ul = u[(size_t)(b*LL + LL-1)*1024 + d];
    float zl = zlast[b*1024 + d];
    float sz = zl / (1.f + expf(-zl));
    yv[b*1024 + d] = (p + ul*Dp[d]) * sz;
  }
}

// ---------------- out_proj (last step only): xout[8][512], weight rows read once ----------------
__global__ __launch_bounds__(256) void k_outproj(const float* __restrict__ yv,
    const float* __restrict__ W, float* __restrict__ xout){
  int tid = threadIdx.x;
  int j = blockIdx.x*8 + (tid>>5);     // 64 blocks -> 512 outputs
  int ks = tid & 31;
  float a[8] = {};
  #pragma unroll
  for(int t=0;t<8;t++){
    int k = ks*4 + t*128;
    float4 wv = *(const float4*)(W + (size_t)j*1024 + k);
    #pragma unroll
    for(int b=0;b<8;b++){
      float4 xv = *(const float4*)(yv + b*1024 + k);
      a[b] += xv.x*wv.x + xv.y*wv.y + xv.z*wv.z + xv.w*wv.w;
    }
  }
  #pragma unroll
  for(int b=0;b<8;b++){
    #pragma unroll
    for(int o=16;o>=1;o>>=1) a[b] += __shfl_xor(a[b], o);
  }
  if(ks==0){
    #pragma unroll
    for(int b=0;b<8;b++) xout[b*512 + j] = a[b];
  }
}

// ---------------- head + denorm -> out[8][96][7], weight rows read once ----------------
__global__ __launch_bounds__(256) void k_head(const float* __restrict__ xout,
    const float* __restrict__ W, const float* __restrict__ hb,
    const float* __restrict__ mean, const float* __restrict__ stdv,
    float* __restrict__ out){
  int tid = threadIdx.x;
  int o = blockIdx.x*8 + (tid>>5);     // 84 blocks -> 672 outputs
  int ks = tid & 31;
  float a[8] = {};
  #pragma unroll
  for(int t=0;t<4;t++){
    int k = ks*4 + t*128;
    float4 wv = *(const float4*)(W + (size_t)o*512 + k);
    #pragma unroll
    for(int b=0;b<8;b++){
      float4 xv = *(const float4*)(xout + b*512 + k);
      a[b] += xv.x*wv.x + xv.y*wv.y + xv.z*wv.z + xv.w*wv.w;
    }
  }
  #pragma unroll
  for(int b=0;b<8;b++){
    #pragma unroll
    for(int oo=16;oo>=1;oo>>=1) a[b] += __shfl_xor(a[b], oo);
  }
  if(ks==0){
    int c = o % 7;
    #pragma unroll
    for(int b=0;b<8;b++){
      float v = a[b] + hb[o];
      out[b*NOUTC + o] = v * stdv[b*CIN + c] + mean[b*CIN + c];
    }
  }
}

extern "C" void kernel_launch(void* const* d_in, const int* in_sizes, int n_in,
                              void* d_out, int out_size, void* d_ws, size_t ws_size,
                              hipStream_t stream) {
  const float* x_enc   = (const float*)d_in[0];
  const float* x_mark  = (const float*)d_in[1];
  const float* tconvw  = (const float*)d_in[4];
  const float* tempw   = (const float*)d_in[5];
  const float* inprojw = (const float*)d_in[6];
  const float* convw   = (const float*)d_in[7];
  const float* convb   = (const float*)d_in[8];
  const float* xprojw  = (const float*)d_in[9];
  const float* dtw     = (const float*)d_in[10];
  const float* dtb     = (const float*)d_in[11];
  const float* alog    = (const float*)d_in[12];
  const float* dpar    = (const float*)d_in[13];
  const float* outw    = (const float*)d_in[14];
  const float* headw   = (const float*)d_in[15];
  const float* headb   = (const float*)d_in[16];

  float* ws    = (float*)d_ws;
  float* mean  = ws;                          // 64
  float* stdv  = ws + 64;                     // 64
  float* xn    = ws + 128;                    // 28,672 -> end 28,800
  ushortT* xbf = (ushortT*)(ws + 28800);      // 2,097,152 u16 = 1,048,576 f -> 1,077,376
  ushortT* wbf = (ushortT*)(ws + 1077376);    // 1,048,576 u16 = 524,288 f -> 1,601,664
  ushortT* xpwbf=(ushortT*)(ws + 1601664);    // 65,536 u16 = 32,768 f -> 1,634,432
  float* xp    = ws + 1634432;                // 4,194,304 -> 5,828,736
  float* zlast = ws + 5828736;                // 8,192 -> 5,836,928
  float* u     = ws + 5836928;                // 4,194,304 -> 10,031,232
  ushortT* ubf = (ushortT*)(ws + 10031232);   // 4,194,304 u16 = 2,097,152 f -> 12,128,384
  float* dbl   = ws + 12128384;               // 262,144 -> 12,390,528
  float* dt    = ws + 12390528;               // 4,194,304 -> 16,584,832
  float* yv    = ws + 16584832;               // 8,192 -> 16,593,024
  float* xout  = ws + 16593024;               // 4,096 -> 16,597,120
  float* out   = (float*)d_out;

  k_stats <<<56, 64, 0, stream>>>(x_enc, mean, stdv, xn);
  k_embed <<<512, 512, 0, stream>>>(xn, x_mark, tconvw, tempw, (__hip_bfloat16*)xbf);
  k_wconv <<<1024, 256, 0, stream>>>(inprojw, wbf);
  k_wconv2<<<64, 256, 0, stream>>>(xprojw, xpwbf);
  k_inproj_mfma<<<dim3(8, 32), 256, 0, stream>>>(xbf, wbf, xp);
  k_zlast <<<32, 256, 0, stream>>>(xbf, wbf, zlast);
  k_dwconv<<<4096, 1024, 0, stream>>>(xp, convw, convb, u, ubf);
  k_xproj_mfma<<<64, 256, 0, stream>>>(ubf, xpwbf, dbl);
  k_dtproj<<<dim3(16, 64), 256, 0, stream>>>(dbl, dtw, dtb, dt);
  k_scan  <<<512, 256, 0, stream>>>(dt, u, dbl, alog, dpar, zlast, yv);
  k_outproj<<<64, 256, 0, stream>>>(yv, outw, xout);
  k_head  <<<84, 256, 0, stream>>>(xout, headw, headb, mean, stdv, out);
}

// Round 6
// 158.507 us; speedup vs baseline: 2.3403x; 1.0652x over previous
//
#include <hip/hip_runtime.h>
#include <hip/hip_bf16.h>
#include <math.h>

#define BB 8
#define LL 512
#define CIN 7
#define MARKN 4
#define DM 512
#define DI 1024
#define DSN 16
#define NOUTC 672
#define NTC 8            // t-chunks in scan

typedef unsigned short ushortT;
typedef __attribute__((ext_vector_type(8))) short short8v;
typedef __attribute__((ext_vector_type(4))) float f32x4;

__device__ __forceinline__ float bf2f(ushortT u){ return __uint_as_float(((unsigned)u)<<16); }

// ---------------- stats: mean/std over L per (b,c), write normalized xn ----------------
__global__ __launch_bounds__(64) void k_stats(const float* __restrict__ xe,
    float* __restrict__ mean, float* __restrict__ stdv, float* __restrict__ xn){
  int bc = blockIdx.x;                 // 56
  int b = bc / CIN, c = bc % CIN;
  int t = threadIdx.x;                 // 64
  const float* base = xe + (b*LL)*CIN + c;
  float v[8]; float s = 0.f;
  #pragma unroll
  for(int i=0;i<8;i++){ v[i] = base[(t + i*64)*CIN]; s += v[i]; }
  #pragma unroll
  for(int o=32;o>=1;o>>=1) s += __shfl_down(s, o);
  float m = __shfl(s, 0) * (1.0f/LL);
  float vs = 0.f;
  #pragma unroll
  for(int i=0;i<8;i++){ float dv = v[i]-m; vs += dv*dv; }
  #pragma unroll
  for(int o=32;o>=1;o>>=1) vs += __shfl_down(vs, o);
  float var = __shfl(vs, 0) * (1.0f/LL);
  float sd = sqrtf(var + 1e-5f);
  float inv = 1.0f / sd;
  if(t == 0){ mean[bc] = m; stdv[bc] = sd; }
  float* xnb = xn + (b*LL)*CIN + c;
  #pragma unroll
  for(int i=0;i<8;i++) xnb[(t + i*64)*CIN] = (v[i]-m)*inv;
}

// ---------------- embedding: token conv (wrap pad) + temporal proj + PE -> bf16 x ----------------
__global__ __launch_bounds__(512) void k_embed(const float* __restrict__ xn,
    const float* __restrict__ xmark, const float* __restrict__ tw,
    const float* __restrict__ tpw, __hip_bfloat16* __restrict__ xo){
  __shared__ float sw[DM*21];          // token_conv_w staged (43KB)
  __shared__ float sxr[10][CIN];       // xn rows l0-1 .. l0+8 (wrap)
  __shared__ float smr[8][MARKN];
  int blk = blockIdx.x;                // 512 = 8 b * 64 chunks
  int b = blk >> 6;
  int l0 = (blk & 63) << 3;            // 8 l per block
  int tid = threadIdx.x;
  for(int i=tid; i<DM*21; i+=512) sw[i] = tw[i];
  if(tid < 70){
    int r = tid / CIN, c = tid % CIN;
    int ls = (l0 - 1 + r + LL) % LL;
    sxr[r][c] = xn[(b*LL + ls)*CIN + c];
  } else if(tid >= 128 && tid < 160){
    int i2 = tid - 128; int r = i2 >> 2, m = i2 & 3;
    smr[r][m] = xmark[(b*LL + l0 + r)*MARKN + m];
  }
  __syncthreads();
  int d = tid;
  float wv[21];
  #pragma unroll
  for(int i=0;i<21;i++) wv[i] = sw[d*21 + i];
  float tv[4];
  #pragma unroll
  for(int m=0;m<4;m++) tv[m] = tpw[d*MARKN + m];
  float divv = expf((float)(2*(d>>1)) * (-0.0179889460390159843f));
  bool isodd = (d & 1) != 0;
  #pragma unroll
  for(int ll=0; ll<8; ll++){
    float acc = 0.f;
    #pragma unroll
    for(int c=0;c<CIN;c++){
      #pragma unroll
      for(int k=0;k<3;k++) acc += sxr[ll+k][c] * wv[c*3+k];
    }
    #pragma unroll
    for(int m=0;m<4;m++) acc += smr[ll][m] * tv[m];
    float ang = (float)(l0+ll) * divv;
    acc += isodd ? cosf(ang) : sinf(ang);
    xo[(size_t)(b*LL + l0 + ll)*DM + d] = __float2bfloat16(acc);
  }
}

// ---------------- convert in_proj_w fp32 -> bf16 (all 2048 rows) ----------------
__global__ __launch_bounds__(256) void k_wconv(const float* __restrict__ w,
    ushortT* __restrict__ wbf){
  int i = (blockIdx.x*256 + threadIdx.x)*4;   // grid 1024 -> 1,048,576 elems
  float4 v = *(const float4*)(w + i);
  __hip_bfloat16 a0 = __float2bfloat16(v.x), a1 = __float2bfloat16(v.y);
  __hip_bfloat16 a2 = __float2bfloat16(v.z), a3 = __float2bfloat16(v.w);
  ushort4 pk;
  pk.x = *(ushortT*)&a0; pk.y = *(ushortT*)&a1; pk.z = *(ushortT*)&a2; pk.w = *(ushortT*)&a3;
  *(ushort4*)(wbf + i) = pk;
}

// ---------------- convert x_proj_w fp32 -> bf16 (64 x 1024) ----------------
__global__ __launch_bounds__(256) void k_wconv2(const float* __restrict__ w,
    ushortT* __restrict__ wbf){
  int i = (blockIdx.x*256 + threadIdx.x)*4;   // grid 64 -> 65,536 elems
  float4 v = *(const float4*)(w + i);
  __hip_bfloat16 a0 = __float2bfloat16(v.x), a1 = __float2bfloat16(v.y);
  __hip_bfloat16 a2 = __float2bfloat16(v.z), a3 = __float2bfloat16(v.w);
  ushort4 pk;
  pk.x = *(ushortT*)&a0; pk.y = *(ushortT*)&a1; pk.z = *(ushortT*)&a2; pk.w = *(ushortT*)&a3;
  *(ushort4*)(wbf + i) = pk;
}

// ---------------- in_proj MFMA GEMM: xp[4096][1024] = Xbf[4096][512] @ Wbf[0:1024]^T ----------------
// 128x128 tile, BK=64, 4 waves (2x2), global_load_lds w16, XOR-swizzled LDS, 2-phase dbuf
__global__ __launch_bounds__(256) void k_inproj_mfma(const ushortT* __restrict__ A,
    const ushortT* __restrict__ Bw, float* __restrict__ C){
  __shared__ ushortT Asl[2][128*64];
  __shared__ ushortT Bsl[2][128*64];
  int tid = threadIdx.x;
  int w = tid >> 6, l = tid & 63;
  int m0 = blockIdx.y * 128, n0 = blockIdx.x * 128;
  int wr = w >> 1, wc = w & 1;
  f32x4 acc[4][4] = {};
  int srow = l >> 3;                    // row within 8-row staging group
  int scolswz = ((l & 7) * 16) ^ (srow << 4);  // pre-swizzled source byte col

#define IP_STAGE(bufi, kt) do{ \
    _Pragma("unroll") \
    for(int i=0;i<4;i++){ \
      int r0 = w*32 + i*8; \
      int r = r0 + srow; \
      const ushortT* gA = A + (size_t)(m0 + r)*512 + (kt)*64 + (scolswz>>1); \
      const ushortT* gB = Bw + (size_t)(n0 + r)*512 + (kt)*64 + (scolswz>>1); \
      __builtin_amdgcn_global_load_lds( \
        (const __attribute__((address_space(1))) unsigned int*)(const void*)gA, \
        (__attribute__((address_space(3))) unsigned int*)(void*)(Asl[bufi] + r0*64), 16, 0, 0); \
      __builtin_amdgcn_global_load_lds( \
        (const __attribute__((address_space(1))) unsigned int*)(const void*)gB, \
        (__attribute__((address_space(3))) unsigned int*)(void*)(Bsl[bufi] + r0*64), 16, 0, 0); \
    } }while(0)

  IP_STAGE(0, 0);
  __syncthreads();
  int cur = 0;
  for(int kt = 0; kt < 8; ++kt){
    if(kt < 7) IP_STAGE(cur^1, kt+1);
    #pragma unroll
    for(int kk=0;kk<2;kk++){
      short8v af[4], bfr[4];
      int cb = kk*64 + (l>>4)*16;       // byte col of this lane's fragment
      #pragma unroll
      for(int mf=0;mf<4;mf++){
        int ar = wr*64 + mf*16 + (l&15);
        af[mf] = *(const short8v*)(Asl[cur] + ar*64 + ((cb ^ ((ar&7)<<4))>>1));
      }
      #pragma unroll
      for(int nf=0;nf<4;nf++){
        int br = wc*64 + nf*16 + (l&15);
        bfr[nf] = *(const short8v*)(Bsl[cur] + br*64 + ((cb ^ ((br&7)<<4))>>1));
      }
      #pragma unroll
      for(int mf=0;mf<4;mf++)
        #pragma unroll
        for(int nf=0;nf<4;nf++)
          acc[mf][nf] = __builtin_amdgcn_mfma_f32_16x16x32_bf16(af[mf], bfr[nf], acc[mf][nf], 0, 0, 0);
    }
    __syncthreads();
    cur ^= 1;
  }
#undef IP_STAGE
  #pragma unroll
  for(int mf=0;mf<4;mf++){
    int rbase = m0 + wr*64 + mf*16 + (l>>4)*4;
    #pragma unroll
    for(int nf=0;nf<4;nf++){
      int col = n0 + wc*64 + nf*16 + (l&15);
      #pragma unroll
      for(int r=0;r<4;r++)
        C[(size_t)(rbase+r)*1024 + col] = acc[mf][nf][r];
    }
  }
}

// ---------------- z_last[8][1024] = x[b,511,:] @ W[1024+d]^T ----------------
__global__ __launch_bounds__(256) void k_zlast(const ushortT* __restrict__ xbf,
    const ushortT* __restrict__ wbf, float* __restrict__ zl){
  int g = blockIdx.x*256 + threadIdx.x;  // grid 32 -> 8192 threads
  int d = g >> 3, b = g & 7;
  const ushortT* xr = xbf + (size_t)(b*LL + LL-1)*512;
  const ushortT* wr = wbf + (size_t)(1024 + d)*512;
  float acc = 0.f;
  for(int k=0;k<512;k+=4){
    ushort4 xv = *(const ushort4*)(xr + k);
    ushort4 wv = *(const ushort4*)(wr + k);
    acc += bf2f(xv.x)*bf2f(wv.x) + bf2f(xv.y)*bf2f(wv.y)
         + bf2f(xv.z)*bf2f(wv.z) + bf2f(xv.w)*bf2f(wv.w);
  }
  zl[b*1024 + d] = acc;
}

// ---------------- causal depthwise conv (D_CONV=4) + silu -> u (fp32 + bf16) ----------------
// 16 l per block, register sliding window: reads 19/16 rows instead of 4x
__global__ __launch_bounds__(1024) void k_dwconv(const float* __restrict__ xp,
    const float* __restrict__ cw, const float* __restrict__ cb,
    float* __restrict__ u, ushortT* __restrict__ ubf){
  int blk = blockIdx.x;                 // 256 = 8 b * 32 lchunks
  int b = blk >> 5, l0 = (blk & 31) * 16;
  int d = threadIdx.x;                  // 1024
  const float4 w4 = *(const float4*)(cw + d*4);
  float bias = cb[d];
  const float* base = xp + (size_t)(b*LL + l0)*1024 + d;
  float x0=0.f, x1=0.f, x2=0.f;
  if(l0 > 0){
    x0 = base[-3*1024]; x1 = base[-2*1024]; x2 = base[-1*1024];
  }
  #pragma unroll
  for(int ll=0; ll<16; ++ll){
    float x3 = base[(size_t)ll*1024];
    float acc = bias + x0*w4.x + x1*w4.y + x2*w4.z + x3*w4.w;
    float s = acc / (1.f + __expf(-acc));
    size_t o = (size_t)(b*LL + l0 + ll)*1024 + d;
    u[o] = s;
    __hip_bfloat16 h = __float2bfloat16(s);
    ubf[o] = *(ushortT*)&h;
    x0 = x1; x1 = x2; x2 = x3;
  }
}

// ---------------- x_proj MFMA GEMM: dbl[4096][64] = ubf[4096][1024] @ Wbf[64][1024]^T ----------------
__global__ __launch_bounds__(256) void k_xproj_mfma(const ushortT* __restrict__ A,
    const ushortT* __restrict__ Bw, float* __restrict__ C){
  __shared__ ushortT Asl[2][64*64];
  __shared__ ushortT Bsl[2][64*64];
  int tid = threadIdx.x;
  int w = tid >> 6, l = tid & 63;
  int m0 = blockIdx.x * 64;
  f32x4 acc[4] = {};
  int srow = l >> 3;
  int scol = ((l & 7) * 16) ^ (srow << 4);   // pre-swizzled source byte col

#define XP_STAGE(bufi, kt) do{ \
    _Pragma("unroll") \
    for(int i=0;i<2;i++){ \
      int r0 = w*16 + i*8; \
      int r = r0 + srow; \
      const ushortT* gA = A + (size_t)(m0 + r)*1024 + (kt)*64 + (scol>>1); \
      const ushortT* gB = Bw + (size_t)r*1024 + (kt)*64 + (scol>>1); \
      __builtin_amdgcn_global_load_lds( \
        (const __attribute__((address_space(1))) unsigned int*)(const void*)gA, \
        (__attribute__((address_space(3))) unsigned int*)(void*)(Asl[bufi] + r0*64), 16, 0, 0); \
      __builtin_amdgcn_global_load_lds( \
        (const __attribute__((address_space(1))) unsigned int*)(const void*)gB, \
        (__attribute__((address_space(3))) unsigned int*)(void*)(Bsl[bufi] + r0*64), 16, 0, 0); \
    } }while(0)

  XP_STAGE(0, 0);
  __syncthreads();
  int cur = 0;
  for(int kt = 0; kt < 16; ++kt){
    if(kt < 15) XP_STAGE(cur^1, kt+1);
    #pragma unroll
    for(int kk=0;kk<2;kk++){
      int cb = kk*64 + (l>>4)*16;
      int ar = w*16 + (l&15);
      short8v af = *(const short8v*)(Asl[cur] + ar*64 + ((cb ^ ((ar&7)<<4))>>1));
      #pragma unroll
      for(int nf=0;nf<4;nf++){
        int br = nf*16 + (l&15);
        short8v bfv = *(const short8v*)(Bsl[cur] + br*64 + ((cb ^ ((br&7)<<4))>>1));
        acc[nf] = __builtin_amdgcn_mfma_f32_16x16x32_bf16(af, bfv, acc[nf], 0, 0, 0);
      }
    }
    __syncthreads();
    cur ^= 1;
  }
#undef XP_STAGE
  int rbase = m0 + w*16 + (l>>4)*4;
  #pragma unroll
  for(int nf=0;nf<4;nf++){
    int col = nf*16 + (l&15);
    #pragma unroll
    for(int r=0;r<4;r++)
      C[(size_t)(rbase+r)*64 + col] = acc[nf][r];
  }
}

// ---------------- dt_proj + softplus: dt[4096][1024] ----------------
__global__ __launch_bounds__(256) void k_dtproj(const float* __restrict__ dbl,
    const float* __restrict__ W, const float* __restrict__ bias, float* __restrict__ dt){
  __shared__ __align__(16) float As[32][68];
  __shared__ __align__(16) float Bs[32][68];
  int tid = threadIdx.x;
  int n0 = blockIdx.x * 64, m0 = blockIdx.y * 64;
  int tx = tid & 15, ty = tid >> 4;
  int row = tid >> 2, lk = (tid & 3) * 8;
  {
    float4 a0 = *(const float4*)(dbl + (size_t)(m0+row)*64 + lk);
    float4 a1 = *(const float4*)(dbl + (size_t)(m0+row)*64 + lk + 4);
    As[lk+0][row]=a0.x; As[lk+1][row]=a0.y; As[lk+2][row]=a0.z; As[lk+3][row]=a0.w;
    As[lk+4][row]=a1.x; As[lk+5][row]=a1.y; As[lk+6][row]=a1.z; As[lk+7][row]=a1.w;
    float4 b0 = *(const float4*)(W + (size_t)(n0+row)*32 + lk);
    float4 b1 = *(const float4*)(W + (size_t)(n0+row)*32 + lk + 4);
    Bs[lk+0][row]=b0.x; Bs[lk+1][row]=b0.y; Bs[lk+2][row]=b0.z; Bs[lk+3][row]=b0.w;
    Bs[lk+4][row]=b1.x; Bs[lk+5][row]=b1.y; Bs[lk+6][row]=b1.z; Bs[lk+7][row]=b1.w;
  }
  __syncthreads();
  float acc[4][4] = {};
  #pragma unroll
  for(int k=0;k<32;k++){
    float4 ar4 = *(const float4*)&As[k][ty*4];
    float4 br4 = *(const float4*)&Bs[k][tx*4];
    float arr[4] = {ar4.x, ar4.y, ar4.z, ar4.w};
    float brr[4] = {br4.x, br4.y, br4.z, br4.w};
    #pragma unroll
    for(int i=0;i<4;i++)
      #pragma unroll
      for(int j=0;j<4;j++) acc[i][j] += arr[i]*brr[j];
  }
  #pragma unroll
  for(int i=0;i<4;i++){
    #pragma unroll
    for(int j=0;j<4;j++){
      int n = n0 + tx*4 + j;
      float v = acc[i][j] + bias[n];
      float sp = (v > 20.f) ? v : __logf(1.f + __expf(v));
      dt[(size_t)(m0+ty*4+i)*1024 + n] = sp;
    }
  }
}

// ---------------- scan chunk: per (b,d,tchunk) compute P,Q s.t. h_out = P*h_in + Q ----------------
// d in lanes (coalesced dt/u loads), B broadcast from LDS, 16 n in registers
__global__ __launch_bounds__(256) void k_scan_chunk(const float* __restrict__ dt,
    const float* __restrict__ u, const float* __restrict__ dbl,
    const float* __restrict__ alog, float* __restrict__ P, float* __restrict__ Q){
  int tc = blockIdx.x;                 // 8 t-chunks of 64
  int dgrp = blockIdx.y;               // 4 groups of 256 d
  int b = blockIdx.z;                  // 8
  int tid = threadIdx.x;               // 256
  int d = dgrp*256 + tid;
  __shared__ float sB[64][16];
  for(int i=tid; i<1024; i+=256){
    int t = i >> 4, n = i & 15;
    sB[t][n] = dbl[(size_t)(b*LL + tc*64 + t)*64 + 32 + n];
  }
  float Ad[16];
  {
    float4 a0 = *(const float4*)(alog + d*16);
    float4 a1 = *(const float4*)(alog + d*16 + 4);
    float4 a2 = *(const float4*)(alog + d*16 + 8);
    float4 a3 = *(const float4*)(alog + d*16 + 12);
    Ad[0]=-__expf(a0.x); Ad[1]=-__expf(a0.y); Ad[2]=-__expf(a0.z); Ad[3]=-__expf(a0.w);
    Ad[4]=-__expf(a1.x); Ad[5]=-__expf(a1.y); Ad[6]=-__expf(a1.z); Ad[7]=-__expf(a1.w);
    Ad[8]=-__expf(a2.x); Ad[9]=-__expf(a2.y); Ad[10]=-__expf(a2.z); Ad[11]=-__expf(a2.w);
    Ad[12]=-__expf(a3.x); Ad[13]=-__expf(a3.y); Ad[14]=-__expf(a3.z); Ad[15]=-__expf(a3.w);
  }
  __syncthreads();
  float h[16];
  #pragma unroll
  for(int n=0;n<16;n++) h[n] = 0.f;
  float Ss = 0.f;
  const float* dtb = dt + (size_t)(b*LL + tc*64)*1024 + d;
  const float* ub  = u  + (size_t)(b*LL + tc*64)*1024 + d;
  #pragma unroll 4
  for(int t=0;t<64;t++){
    float dtv = dtb[(size_t)t*1024];
    float uv  = ub [(size_t)t*1024];
    float wt = dtv * uv;
    Ss += dtv;
    float4 B0 = *(const float4*)&sB[t][0];
    float4 B1 = *(const float4*)&sB[t][4];
    float4 B2 = *(const float4*)&sB[t][8];
    float4 B3 = *(const float4*)&sB[t][12];
    float Bv[16] = {B0.x,B0.y,B0.z,B0.w, B1.x,B1.y,B1.z,B1.w,
                    B2.x,B2.y,B2.z,B2.w, B3.x,B3.y,B3.z,B3.w};
    #pragma unroll
    for(int n=0;n<16;n++){
      float e = __expf(dtv * Ad[n]);
      h[n] = h[n]*e + wt*Bv[n];
    }
  }
  size_t o = ((size_t)(tc*8 + b)*1024 + d)*16;
  #pragma unroll
  for(int n4=0;n4<4;n4++){
    float4 qv = make_float4(h[n4*4], h[n4*4+1], h[n4*4+2], h[n4*4+3]);
    *(float4*)(Q + o + n4*4) = qv;
    float4 pv = make_float4(__expf(Ss*Ad[n4*4]), __expf(Ss*Ad[n4*4+1]),
                            __expf(Ss*Ad[n4*4+2]), __expf(Ss*Ad[n4*4+3]));
    *(float4*)(P + o + n4*4) = pv;
  }
}

// ---------------- combine chunks + C-dot + gating -> yv[b][d] ----------------
__global__ __launch_bounds__(1024) void k_scan_combine(const float* __restrict__ P,
    const float* __restrict__ Q, const float* __restrict__ dbl,
    const float* __restrict__ u, const float* __restrict__ Dp,
    const float* __restrict__ zlast, float* __restrict__ yv){
  int b = blockIdx.x;                  // 8
  int d = threadIdx.x;                 // 1024
  __shared__ float sC[16];
  if(d < 16) sC[d] = dbl[(size_t)(b*LL + LL-1)*64 + 48 + d];
  __syncthreads();
  float h[16];
  #pragma unroll
  for(int n=0;n<16;n++) h[n] = 0.f;
  #pragma unroll
  for(int c=0;c<NTC;c++){
    size_t o = ((size_t)(c*8 + b)*1024 + d)*16;
    #pragma unroll
    for(int n4=0;n4<4;n4++){
      float4 pv = *(const float4*)(P + o + n4*4);
      float4 qv = *(const float4*)(Q + o + n4*4);
      h[n4*4+0] = pv.x*h[n4*4+0] + qv.x;
      h[n4*4+1] = pv.y*h[n4*4+1] + qv.y;
      h[n4*4+2] = pv.z*h[n4*4+2] + qv.z;
      h[n4*4+3] = pv.w*h[n4*4+3] + qv.w;
    }
  }
  float y = 0.f;
  #pragma unroll
  for(int n=0;n<16;n++) y += sC[n]*h[n];
  float ul = u[(size_t)(b*LL + LL-1)*1024 + d];
  float zl = zlast[b*1024 + d];
  float sz = zl / (1.f + __expf(-zl));
  yv[b*1024 + d] = (y + ul*Dp[d]) * sz;
}

// ---------------- out_proj (last step only): xout[8][512], weight rows read once ----------------
__global__ __launch_bounds__(256) void k_outproj(const float* __restrict__ yv,
    const float* __restrict__ W, float* __restrict__ xout){
  int tid = threadIdx.x;
  int j = blockIdx.x*8 + (tid>>5);     // 64 blocks -> 512 outputs
  int ks = tid & 31;
  float a[8] = {};
  #pragma unroll
  for(int t=0;t<8;t++){
    int k = ks*4 + t*128;
    float4 wv = *(const float4*)(W + (size_t)j*1024 + k);
    #pragma unroll
    for(int b=0;b<8;b++){
      float4 xv = *(const float4*)(yv + b*1024 + k);
      a[b] += xv.x*wv.x + xv.y*wv.y + xv.z*wv.z + xv.w*wv.w;
    }
  }
  #pragma unroll
  for(int b=0;b<8;b++){
    #pragma unroll
    for(int o=16;o>=1;o>>=1) a[b] += __shfl_xor(a[b], o);
  }
  if(ks==0){
    #pragma unroll
    for(int b=0;b<8;b++) xout[b*512 + j] = a[b];
  }
}

// ---------------- head + denorm -> out[8][96][7], weight rows read once ----------------
__global__ __launch_bounds__(256) void k_head(const float* __restrict__ xout,
    const float* __restrict__ W, const float* __restrict__ hb,
    const float* __restrict__ mean, const float* __restrict__ stdv,
    float* __restrict__ out){
  int tid = threadIdx.x;
  int o = blockIdx.x*8 + (tid>>5);     // 84 blocks -> 672 outputs
  int ks = tid & 31;
  float a[8] = {};
  #pragma unroll
  for(int t=0;t<4;t++){
    int k = ks*4 + t*128;
    float4 wv = *(const float4*)(W + (size_t)o*512 + k);
    #pragma unroll
    for(int b=0;b<8;b++){
      float4 xv = *(const float4*)(xout + b*512 + k);
      a[b] += xv.x*wv.x + xv.y*wv.y + xv.z*wv.z + xv.w*wv.w;
    }
  }
  #pragma unroll
  for(int b=0;b<8;b++){
    #pragma unroll
    for(int oo=16;oo>=1;oo>>=1) a[b] += __shfl_xor(a[b], oo);
  }
  if(ks==0){
    int c = o % 7;
    #pragma unroll
    for(int b=0;b<8;b++){
      float v = a[b] + hb[o];
      out[b*NOUTC + o] = v * stdv[b*CIN + c] + mean[b*CIN + c];
    }
  }
}

extern "C" void kernel_launch(void* const* d_in, const int* in_sizes, int n_in,
                              void* d_out, int out_size, void* d_ws, size_t ws_size,
                              hipStream_t stream) {
  const float* x_enc   = (const float*)d_in[0];
  const float* x_mark  = (const float*)d_in[1];
  const float* tconvw  = (const float*)d_in[4];
  const float* tempw   = (const float*)d_in[5];
  const float* inprojw = (const float*)d_in[6];
  const float* convw   = (const float*)d_in[7];
  const float* convb   = (const float*)d_in[8];
  const float* xprojw  = (const float*)d_in[9];
  const float* dtw     = (const float*)d_in[10];
  const float* dtb     = (const float*)d_in[11];
  const float* alog    = (const float*)d_in[12];
  const float* dpar    = (const float*)d_in[13];
  const float* outw    = (const float*)d_in[14];
  const float* headw   = (const float*)d_in[15];
  const float* headb   = (const float*)d_in[16];

  float* ws    = (float*)d_ws;
  float* mean  = ws;                          // 64
  float* stdv  = ws + 64;                     // 64
  float* xn    = ws + 128;                    // 28,672 -> end 28,800
  ushortT* xbf = (ushortT*)(ws + 28800);      // 1,048,576 f -> 1,077,376
  ushortT* wbf = (ushortT*)(ws + 1077376);    // 524,288 f -> 1,601,664
  ushortT* xpwbf=(ushortT*)(ws + 1601664);    // 32,768 f -> 1,634,432
  float* xp    = ws + 1634432;                // 4,194,304 -> 5,828,736
  float* zlast = ws + 5828736;                // 8,192 -> 5,836,928
  float* u     = ws + 5836928;                // 4,194,304 -> 10,031,232
  ushortT* ubf = (ushortT*)(ws + 10031232);   // 2,097,152 f -> 12,128,384
  float* dbl   = ws + 12128384;               // 262,144 -> 12,390,528
  float* dt    = ws + 12390528;               // 4,194,304 -> 16,584,832
  float* yv    = ws + 16584832;               // 8,192 -> 16,593,024
  float* xout  = ws + 16593024;               // 4,096 -> 16,597,120
  // P/Q overlay the xp region (dead after k_dwconv): 2 x 1,048,576 floats
  float* Pb    = xp;                          // 1,048,576
  float* Qb    = xp + 1048576;                // 1,048,576
  float* out   = (float*)d_out;

  k_stats <<<56, 64, 0, stream>>>(x_enc, mean, stdv, xn);
  k_embed <<<512, 512, 0, stream>>>(xn, x_mark, tconvw, tempw, (__hip_bfloat16*)xbf);
  k_wconv <<<1024, 256, 0, stream>>>(inprojw, wbf);
  k_wconv2<<<64, 256, 0, stream>>>(xprojw, xpwbf);
  k_inproj_mfma<<<dim3(8, 32), 256, 0, stream>>>(xbf, wbf, xp);
  k_zlast <<<32, 256, 0, stream>>>(xbf, wbf, zlast);
  k_dwconv<<<256, 1024, 0, stream>>>(xp, convw, convb, u, ubf);
  k_xproj_mfma<<<64, 256, 0, stream>>>(ubf, xpwbf, dbl);
  k_dtproj<<<dim3(16, 64), 256, 0, stream>>>(dbl, dtw, dtb, dt);
  k_scan_chunk<<<dim3(NTC, 4, 8), 256, 0, stream>>>(dt, u, dbl, alog, Pb, Qb);
  k_scan_combine<<<8, 1024, 0, stream>>>(Pb, Qb, dbl, u, dpar, zlast, yv);
  k_outproj<<<64, 256, 0, stream>>>(yv, outw, xout);
  k_head  <<<84, 256, 0, stream>>>(xout, headw, headb, mean, stdv, out);
}

// Round 8
// 124.165 us; speedup vs baseline: 2.9876x; 1.2766x over previous
//
#include <hip/hip_runtime.h>
#include <hip/hip_bf16.h>
#include <math.h>

#define BB 8
#define LL 512
#define CIN 7
#define MARKN 4
#define DM 512
#define DI 1024
#define DSN 16
#define NOUTC 672
#define NTC 8            // t-chunks in scan

typedef unsigned short ushortT;
typedef __attribute__((ext_vector_type(8))) short short8v;
typedef __attribute__((ext_vector_type(4))) float f32x4;

__device__ __forceinline__ float bf2f(ushortT u){ return __uint_as_float(((unsigned)u)<<16); }
__device__ __forceinline__ ushortT f2bf(float f){ __hip_bfloat16 h = __float2bfloat16(f); return *(ushortT*)&h; }

// ---------------- stats: mean/std over L per (b,c), write normalized xn ----------------
__global__ __launch_bounds__(64) void k_stats(const float* __restrict__ xe,
    float* __restrict__ mean, float* __restrict__ stdv, float* __restrict__ xn){
  int bc = blockIdx.x;                 // 56
  int b = bc / CIN, c = bc % CIN;
  int t = threadIdx.x;                 // 64
  const float* base = xe + (b*LL)*CIN + c;
  float v[8]; float s = 0.f;
  #pragma unroll
  for(int i=0;i<8;i++){ v[i] = base[(t + i*64)*CIN]; s += v[i]; }
  #pragma unroll
  for(int o=32;o>=1;o>>=1) s += __shfl_down(s, o);
  float m = __shfl(s, 0) * (1.0f/LL);
  float vs = 0.f;
  #pragma unroll
  for(int i=0;i<8;i++){ float dv = v[i]-m; vs += dv*dv; }
  #pragma unroll
  for(int o=32;o>=1;o>>=1) vs += __shfl_down(vs, o);
  float var = __shfl(vs, 0) * (1.0f/LL);
  float sd = sqrtf(var + 1e-5f);
  float inv = 1.0f / sd;
  if(t == 0){ mean[bc] = m; stdv[bc] = sd; }
  float* xnb = xn + (b*LL)*CIN + c;
  #pragma unroll
  for(int i=0;i<8;i++) xnb[(t + i*64)*CIN] = (v[i]-m)*inv;
}

// ---------------- embedding: token conv (wrap pad) + temporal proj + PE -> bf16 x ----------------
__global__ __launch_bounds__(512) void k_embed(const float* __restrict__ xn,
    const float* __restrict__ xmark, const float* __restrict__ tw,
    const float* __restrict__ tpw, __hip_bfloat16* __restrict__ xo){
  __shared__ float sw[DM*21];          // token_conv_w staged (43KB)
  __shared__ float sxr[10][CIN];       // xn rows l0-1 .. l0+8 (wrap)
  __shared__ float smr[8][MARKN];
  int blk = blockIdx.x;                // 512 = 8 b * 64 chunks
  int b = blk >> 6;
  int l0 = (blk & 63) << 3;            // 8 l per block
  int tid = threadIdx.x;
  for(int i=tid; i<DM*21; i+=512) sw[i] = tw[i];
  if(tid < 70){
    int r = tid / CIN, c = tid % CIN;
    int ls = (l0 - 1 + r + LL) % LL;
    sxr[r][c] = xn[(b*LL + ls)*CIN + c];
  } else if(tid >= 128 && tid < 160){
    int i2 = tid - 128; int r = i2 >> 2, m = i2 & 3;
    smr[r][m] = xmark[(b*LL + l0 + r)*MARKN + m];
  }
  __syncthreads();
  int d = tid;
  float wv[21];
  #pragma unroll
  for(int i=0;i<21;i++) wv[i] = sw[d*21 + i];
  float tv[4];
  #pragma unroll
  for(int m=0;m<4;m++) tv[m] = tpw[d*MARKN + m];
  float divv = expf((float)(2*(d>>1)) * (-0.0179889460390159843f));
  bool isodd = (d & 1) != 0;
  #pragma unroll
  for(int ll=0; ll<8; ll++){
    float acc = 0.f;
    #pragma unroll
    for(int c=0;c<CIN;c++){
      #pragma unroll
      for(int k=0;k<3;k++) acc += sxr[ll+k][c] * wv[c*3+k];
    }
    #pragma unroll
    for(int m=0;m<4;m++) acc += smr[ll][m] * tv[m];
    float ang = (float)(l0+ll) * divv;
    acc += isodd ? cosf(ang) : sinf(ang);
    xo[(size_t)(b*LL + l0 + ll)*DM + d] = __float2bfloat16(acc);
  }
}

// ---------------- prep: wbf convert + W_dt = dtw@xpw[0:32] + wcomb tail ----------------
// blk 0-1023:   in_proj_w fp32 -> bf16 (1M elems)
// blk 1024-1279: W_dt[n][k] = sum_r dtw[n][r]*xpw[r][k] -> wcomb rows 0-1023 (bf16)
// blk 1280-1407: wcomb rows 1024-1055 = xpw rows 32-63 (bf16); rows 1056-1151 = 0
__global__ __launch_bounds__(256) void k_prep(const float* __restrict__ w_in,
    const float* __restrict__ dtw, const float* __restrict__ xpw,
    ushortT* __restrict__ wbf, ushortT* __restrict__ wcomb){
  int blk = blockIdx.x, tid = threadIdx.x;
  if(blk < 1024){
    int i = (blk*256 + tid)*4;
    float4 v = *(const float4*)(w_in + i);
    ushort4 pk; pk.x=f2bf(v.x); pk.y=f2bf(v.y); pk.z=f2bf(v.z); pk.w=f2bf(v.w);
    *(ushort4*)(wbf + i) = pk;
  } else if(blk < 1280){
    int n0 = (blk - 1024)*4;
    int k0 = tid*4;
    float acc[4][4] = {};
    for(int r=0;r<32;r++){
      float4 xv = *(const float4*)(xpw + r*1024 + k0);
      #pragma unroll
      for(int nn=0;nn<4;nn++){
        float wv = dtw[(n0+nn)*32 + r];
        acc[nn][0] += wv*xv.x; acc[nn][1] += wv*xv.y;
        acc[nn][2] += wv*xv.z; acc[nn][3] += wv*xv.w;
      }
    }
    #pragma unroll
    for(int nn=0;nn<4;nn++){
      ushort4 pk;
      pk.x=f2bf(acc[nn][0]); pk.y=f2bf(acc[nn][1]);
      pk.z=f2bf(acc[nn][2]); pk.w=f2bf(acc[nn][3]);
      *(ushort4*)(wcomb + (size_t)(n0+nn)*1024 + k0) = pk;
    }
  } else {
    int row = 1024 + (blk - 1280);     // 1024..1151
    int k0 = tid*4;
    ushort4 pk;
    if(row < 1056){
      float4 v = *(const float4*)(xpw + (size_t)(row-1024+32)*1024 + k0);
      pk.x=f2bf(v.x); pk.y=f2bf(v.y); pk.z=f2bf(v.z); pk.w=f2bf(v.w);
    } else { pk.x=0; pk.y=0; pk.z=0; pk.w=0; }
    *(ushort4*)(wcomb + (size_t)row*1024 + k0) = pk;
  }
}

// ---------------- in_proj MFMA GEMM: xp[4096][1024] = Xbf[4096][512] @ Wbf[0:1024]^T ----------------
__global__ __launch_bounds__(256) void k_inproj_mfma(const ushortT* __restrict__ A,
    const ushortT* __restrict__ Bw, float* __restrict__ C){
  __shared__ ushortT Asl[2][128*64];
  __shared__ ushortT Bsl[2][128*64];
  int tid = threadIdx.x;
  int w = tid >> 6, l = tid & 63;
  int m0 = blockIdx.y * 128, n0 = blockIdx.x * 128;
  int wr = w >> 1, wc = w & 1;
  f32x4 acc[4][4] = {};
  int srow = l >> 3;
  int scolswz = ((l & 7) * 16) ^ (srow << 4);

#define IP_STAGE(bufi, kt) do{ \
    _Pragma("unroll") \
    for(int i=0;i<4;i++){ \
      int r0 = w*32 + i*8; \
      int r = r0 + srow; \
      const ushortT* gA = A + (size_t)(m0 + r)*512 + (kt)*64 + (scolswz>>1); \
      const ushortT* gB = Bw + (size_t)(n0 + r)*512 + (kt)*64 + (scolswz>>1); \
      __builtin_amdgcn_global_load_lds( \
        (const __attribute__((address_space(1))) unsigned int*)(const void*)gA, \
        (__attribute__((address_space(3))) unsigned int*)(void*)(Asl[bufi] + r0*64), 16, 0, 0); \
      __builtin_amdgcn_global_load_lds( \
        (const __attribute__((address_space(1))) unsigned int*)(const void*)gB, \
        (__attribute__((address_space(3))) unsigned int*)(void*)(Bsl[bufi] + r0*64), 16, 0, 0); \
    } }while(0)

  IP_STAGE(0, 0);
  __syncthreads();
  int cur = 0;
  for(int kt = 0; kt < 8; ++kt){
    if(kt < 7) IP_STAGE(cur^1, kt+1);
    #pragma unroll
    for(int kk=0;kk<2;kk++){
      short8v af[4], bfr[4];
      int cb = kk*64 + (l>>4)*16;
      #pragma unroll
      for(int mf=0;mf<4;mf++){
        int ar = wr*64 + mf*16 + (l&15);
        af[mf] = *(const short8v*)(Asl[cur] + ar*64 + ((cb ^ ((ar&7)<<4))>>1));
      }
      #pragma unroll
      for(int nf=0;nf<4;nf++){
        int br = wc*64 + nf*16 + (l&15);
        bfr[nf] = *(const short8v*)(Bsl[cur] + br*64 + ((cb ^ ((br&7)<<4))>>1));
      }
      #pragma unroll
      for(int mf=0;mf<4;mf++)
        #pragma unroll
        for(int nf=0;nf<4;nf++)
          acc[mf][nf] = __builtin_amdgcn_mfma_f32_16x16x32_bf16(af[mf], bfr[nf], acc[mf][nf], 0, 0, 0);
    }
    __syncthreads();
    cur ^= 1;
  }
#undef IP_STAGE
  #pragma unroll
  for(int mf=0;mf<4;mf++){
    int rbase = m0 + wr*64 + mf*16 + (l>>4)*4;
    #pragma unroll
    for(int nf=0;nf<4;nf++){
      int col = n0 + wc*64 + nf*16 + (l&15);
      #pragma unroll
      for(int r=0;r<4;r++)
        C[(size_t)(rbase+r)*1024 + col] = acc[mf][nf][r];
    }
  }
}

// ---------------- causal depthwise conv (D_CONV=4) + silu -> ubf (bf16 only) ----------------
__global__ __launch_bounds__(1024) void k_dwconv(const float* __restrict__ xp,
    const float* __restrict__ cw, const float* __restrict__ cb,
    ushortT* __restrict__ ubf){
  int blk = blockIdx.x;                 // 256 = 8 b * 32 lchunks
  int b = blk >> 5, l0 = (blk & 31) * 16;
  int d = threadIdx.x;                  // 1024
  const float4 w4 = *(const float4*)(cw + d*4);
  float bias = cb[d];
  const float* base = xp + (size_t)(b*LL + l0)*1024 + d;
  float x0=0.f, x1=0.f, x2=0.f;
  if(l0 > 0){
    x0 = base[-3*1024]; x1 = base[-2*1024]; x2 = base[-1*1024];
  }
  #pragma unroll
  for(int ll=0; ll<16; ++ll){
    float x3 = base[(size_t)ll*1024];
    float acc = bias + x0*w4.x + x1*w4.y + x2*w4.z + x3*w4.w;
    float s = acc / (1.f + __expf(-acc));
    ubf[(size_t)(b*LL + l0 + ll)*1024 + d] = f2bf(s);
    x0 = x1; x1 = x2; x2 = x3;
  }
}

// ---------------- combined x_proj+dt_proj MFMA: [4096][1152] = ubf @ wcomb^T ----------------
// cols 0-1023 -> dt = softplus(.+dtb) stored bf16; cols 1024-1055 -> dbl32 (B|C); rest discard
__global__ __launch_bounds__(256) void k_xdt_mfma(const ushortT* __restrict__ A,
    const ushortT* __restrict__ Bw, const float* __restrict__ dtb,
    ushortT* __restrict__ dtbf, float* __restrict__ dbl32){
  __shared__ ushortT Asl[2][128*64];
  __shared__ ushortT Bsl[2][128*64];
  int tid = threadIdx.x;
  int w = tid >> 6, l = tid & 63;
  int m0 = blockIdx.y * 128, n0 = blockIdx.x * 128;
  int wr = w >> 1, wc = w & 1;
  f32x4 acc[4][4] = {};
  int srow = l >> 3;
  int scolswz = ((l & 7) * 16) ^ (srow << 4);

#define XD_STAGE(bufi, kt) do{ \
    _Pragma("unroll") \
    for(int i=0;i<4;i++){ \
      int r0 = w*32 + i*8; \
      int r = r0 + srow; \
      const ushortT* gA = A + (size_t)(m0 + r)*1024 + (kt)*64 + (scolswz>>1); \
      const ushortT* gB = Bw + (size_t)(n0 + r)*1024 + (kt)*64 + (scolswz>>1); \
      __builtin_amdgcn_global_load_lds( \
        (const __attribute__((address_space(1))) unsigned int*)(const void*)gA, \
        (__attribute__((address_space(3))) unsigned int*)(void*)(Asl[bufi] + r0*64), 16, 0, 0); \
      __builtin_amdgcn_global_load_lds( \
        (const __attribute__((address_space(1))) unsigned int*)(const void*)gB, \
        (__attribute__((address_space(3))) unsigned int*)(void*)(Bsl[bufi] + r0*64), 16, 0, 0); \
    } }while(0)

  XD_STAGE(0, 0);
  __syncthreads();
  int cur = 0;
  for(int kt = 0; kt < 16; ++kt){
    if(kt < 15) XD_STAGE(cur^1, kt+1);
    #pragma unroll
    for(int kk=0;kk<2;kk++){
      short8v af[4], bfr[4];
      int cb = kk*64 + (l>>4)*16;
      #pragma unroll
      for(int mf=0;mf<4;mf++){
        int ar = wr*64 + mf*16 + (l&15);
        af[mf] = *(const short8v*)(Asl[cur] + ar*64 + ((cb ^ ((ar&7)<<4))>>1));
      }
      #pragma unroll
      for(int nf=0;nf<4;nf++){
        int br = wc*64 + nf*16 + (l&15);
        bfr[nf] = *(const short8v*)(Bsl[cur] + br*64 + ((cb ^ ((br&7)<<4))>>1));
      }
      #pragma unroll
      for(int mf=0;mf<4;mf++)
        #pragma unroll
        for(int nf=0;nf<4;nf++)
          acc[mf][nf] = __builtin_amdgcn_mfma_f32_16x16x32_bf16(af[mf], bfr[nf], acc[mf][nf], 0, 0, 0);
    }
    __syncthreads();
    cur ^= 1;
  }
#undef XD_STAGE
  #pragma unroll
  for(int mf=0;mf<4;mf++){
    int rbase = m0 + wr*64 + mf*16 + (l>>4)*4;
    #pragma unroll
    for(int nf=0;nf<4;nf++){
      int col = n0 + wc*64 + nf*16 + (l&15);
      if(col < 1024){
        float bb = dtb[col];
        #pragma unroll
        for(int r=0;r<4;r++){
          float v = acc[mf][nf][r] + bb;
          float sp = (v > 20.f) ? v : __logf(1.f + __expf(v));
          dtbf[(size_t)(rbase+r)*1024 + col] = f2bf(sp);
        }
      } else if(col < 1056){
        #pragma unroll
        for(int r=0;r<4;r++)
          dbl32[(size_t)(rbase+r)*32 + (col-1024)] = acc[mf][nf][r];
      }
    }
  }
}

// ---------------- scan chunk: per (b,d,tchunk) compute P,Q s.t. h_out = P*h_in + Q ----------------
__global__ __launch_bounds__(256) void k_scan_chunk(const ushortT* __restrict__ dtbf,
    const ushortT* __restrict__ ubf, const float* __restrict__ dbl32,
    const float* __restrict__ alog, float* __restrict__ P, float* __restrict__ Q){
  int tc = blockIdx.x;                 // 8 t-chunks of 64
  int dgrp = blockIdx.y;               // 4 groups of 256 d
  int b = blockIdx.z;                  // 8
  int tid = threadIdx.x;               // 256
  int d = dgrp*256 + tid;
  __shared__ float sB[64][16];
  for(int i=tid; i<1024; i+=256){
    int t = i >> 4, n = i & 15;
    sB[t][n] = dbl32[(size_t)(b*LL + tc*64 + t)*32 + n];
  }
  float Ad[16];
  {
    float4 a0 = *(const float4*)(alog + d*16);
    float4 a1 = *(const float4*)(alog + d*16 + 4);
    float4 a2 = *(const float4*)(alog + d*16 + 8);
    float4 a3 = *(const float4*)(alog + d*16 + 12);
    Ad[0]=-__expf(a0.x); Ad[1]=-__expf(a0.y); Ad[2]=-__expf(a0.z); Ad[3]=-__expf(a0.w);
    Ad[4]=-__expf(a1.x); Ad[5]=-__expf(a1.y); Ad[6]=-__expf(a1.z); Ad[7]=-__expf(a1.w);
    Ad[8]=-__expf(a2.x); Ad[9]=-__expf(a2.y); Ad[10]=-__expf(a2.z); Ad[11]=-__expf(a2.w);
    Ad[12]=-__expf(a3.x); Ad[13]=-__expf(a3.y); Ad[14]=-__expf(a3.z); Ad[15]=-__expf(a3.w);
  }
  __syncthreads();
  float h[16];
  #pragma unroll
  for(int n=0;n<16;n++) h[n] = 0.f;
  float Ss = 0.f;
  const ushortT* dtp = dtbf + (size_t)(b*LL + tc*64)*1024 + d;
  const ushortT* up  = ubf  + (size_t)(b*LL + tc*64)*1024 + d;
  #pragma unroll 4
  for(int t=0;t<64;t++){
    float dtv = bf2f(dtp[(size_t)t*1024]);
    float uv  = bf2f(up [(size_t)t*1024]);
    float wt = dtv * uv;
    Ss += dtv;
    float4 B0 = *(const float4*)&sB[t][0];
    float4 B1 = *(const float4*)&sB[t][4];
    float4 B2 = *(const float4*)&sB[t][8];
    float4 B3 = *(const float4*)&sB[t][12];
    float Bv[16] = {B0.x,B0.y,B0.z,B0.w, B1.x,B1.y,B1.z,B1.w,
                    B2.x,B2.y,B2.z,B2.w, B3.x,B3.y,B3.z,B3.w};
    #pragma unroll
    for(int n=0;n<16;n++){
      float e = __expf(dtv * Ad[n]);
      h[n] = h[n]*e + wt*Bv[n];
    }
  }
  size_t o = ((size_t)(tc*8 + b)*1024 + d)*16;
  #pragma unroll
  for(int n4=0;n4<4;n4++){
    float4 qv = make_float4(h[n4*4], h[n4*4+1], h[n4*4+2], h[n4*4+3]);
    *(float4*)(Q + o + n4*4) = qv;
    float4 pv = make_float4(__expf(Ss*Ad[n4*4]), __expf(Ss*Ad[n4*4+1]),
                            __expf(Ss*Ad[n4*4+2]), __expf(Ss*Ad[n4*4+3]));
    *(float4*)(P + o + n4*4) = pv;
  }
}

// ---------------- combine chunks + z_last dot + C-dot + gating -> yv[b][d] ----------------
// 128 blocks x 64 thr: thread = (b,d); zlast folded in (wbf z-half rows)
__global__ __launch_bounds__(64) void k_scan_combine(const float* __restrict__ P,
    const float* __restrict__ Q, const float* __restrict__ dbl32,
    const ushortT* __restrict__ ubf, const ushortT* __restrict__ xbf,
    const ushortT* __restrict__ wbf, const float* __restrict__ Dp,
    float* __restrict__ yv){
  int gid = blockIdx.x*64 + threadIdx.x;   // 8192
  int d = gid >> 3, b = gid & 7;
  // z_last: dot(xbf[b,511,:], wbf[1024+d,:]) over K=512
  const ushortT* xr = xbf + (size_t)(b*LL + LL-1)*512;
  const ushortT* wr = wbf + (size_t)(1024 + d)*512;
  float zl = 0.f;
  for(int k=0;k<512;k+=4){
    ushort4 xv = *(const ushort4*)(xr + k);
    ushort4 wv = *(const ushort4*)(wr + k);
    zl += bf2f(xv.x)*bf2f(wv.x) + bf2f(xv.y)*bf2f(wv.y)
        + bf2f(xv.z)*bf2f(wv.z) + bf2f(xv.w)*bf2f(wv.w);
  }
  float h[16];
  #pragma unroll
  for(int n=0;n<16;n++) h[n] = 0.f;
  #pragma unroll
  for(int c=0;c<NTC;c++){
    size_t o = ((size_t)(c*8 + b)*1024 + d)*16;
    #pragma unroll
    for(int n4=0;n4<4;n4++){
      float4 pv = *(const float4*)(P + o + n4*4);
      float4 qv = *(const float4*)(Q + o + n4*4);
      h[n4*4+0] = pv.x*h[n4*4+0] + qv.x;
      h[n4*4+1] = pv.y*h[n4*4+1] + qv.y;
      h[n4*4+2] = pv.z*h[n4*4+2] + qv.z;
      h[n4*4+3] = pv.w*h[n4*4+3] + qv.w;
    }
  }
  const float* Crow = dbl32 + (size_t)(b*LL + LL-1)*32 + 16;
  float y = 0.f;
  #pragma unroll
  for(int n=0;n<16;n++) y += Crow[n]*h[n];
  float ul = bf2f(ubf[(size_t)(b*LL + LL-1)*1024 + d]);
  float sz = zl / (1.f + __expf(-zl));
  yv[b*1024 + d] = (y + ul*Dp[d]) * sz;
}

// ---------------- out_proj (last step only): xout[8][512] ----------------
__global__ __launch_bounds__(256) void k_outproj(const float* __restrict__ yv,
    const float* __restrict__ W, float* __restrict__ xout){
  int tid = threadIdx.x;
  int j = blockIdx.x*8 + (tid>>5);     // 64 blocks -> 512 outputs
  int ks = tid & 31;
  float a[8] = {};
  #pragma unroll
  for(int t=0;t<8;t++){
    int k = ks*4 + t*128;
    float4 wv = *(const float4*)(W + (size_t)j*1024 + k);
    #pragma unroll
    for(int b=0;b<8;b++){
      float4 xv = *(const float4*)(yv + b*1024 + k);
      a[b] += xv.x*wv.x + xv.y*wv.y + xv.z*wv.z + xv.w*wv.w;
    }
  }
  #pragma unroll
  for(int b=0;b<8;b++){
    #pragma unroll
    for(int o=16;o>=1;o>>=1) a[b] += __shfl_xor(a[b], o);
  }
  if(ks==0){
    #pragma unroll
    for(int b=0;b<8;b++) xout[b*512 + j] = a[b];
  }
}

// ---------------- head + denorm -> out[8][96][7] ----------------
__global__ __launch_bounds__(256) void k_head(const float* __restrict__ xout,
    const float* __restrict__ W, const float* __restrict__ hb,
    const float* __restrict__ mean, const float* __restrict__ stdv,
    float* __restrict__ out){
  int tid = threadIdx.x;
  int o = blockIdx.x*8 + (tid>>5);     // 84 blocks -> 672 outputs
  int ks = tid & 31;
  float a[8] = {};
  #pragma unroll
  for(int t=0;t<4;t++){
    int k = ks*4 + t*128;
    float4 wv = *(const float4*)(W + (size_t)o*512 + k);
    #pragma unroll
    for(int b=0;b<8;b++){
      float4 xv = *(const float4*)(xout + b*512 + k);
      a[b] += xv.x*wv.x + xv.y*wv.y + xv.z*wv.z + xv.w*wv.w;
    }
  }
  #pragma unroll
  for(int b=0;b<8;b++){
    #pragma unroll
    for(int oo=16;oo>=1;oo>>=1) a[b] += __shfl_xor(a[b], oo);
  }
  if(ks==0){
    int c = o % 7;
    #pragma unroll
    for(int b=0;b<8;b++){
      float v = a[b] + hb[o];
      out[b*NOUTC + o] = v * stdv[b*CIN + c] + mean[b*CIN + c];
    }
  }
}

extern "C" void kernel_launch(void* const* d_in, const int* in_sizes, int n_in,
                              void* d_out, int out_size, void* d_ws, size_t ws_size,
                              hipStream_t stream) {
  const float* x_enc   = (const float*)d_in[0];
  const float* x_mark  = (const float*)d_in[1];
  const float* tconvw  = (const float*)d_in[4];
  const float* tempw   = (const float*)d_in[5];
  const float* inprojw = (const float*)d_in[6];
  const float* convw   = (const float*)d_in[7];
  const float* convb   = (const float*)d_in[8];
  const float* xprojw  = (const float*)d_in[9];
  const float* dtw     = (const float*)d_in[10];
  const float* dtb     = (const float*)d_in[11];
  const float* alog    = (const float*)d_in[12];
  const float* dpar    = (const float*)d_in[13];
  const float* outw    = (const float*)d_in[14];
  const float* headw   = (const float*)d_in[15];
  const float* headb   = (const float*)d_in[16];

  float* ws    = (float*)d_ws;
  float* mean  = ws;                          // 64
  float* stdv  = ws + 64;                     // 64
  float* xn    = ws + 128;                    // 28,672 -> 28,800
  ushortT* xbf = (ushortT*)(ws + 28800);      // [4096][512]  bf16 -> 1,077,376
  ushortT* wbf = (ushortT*)(ws + 1077376);    // [2048][512]  bf16 -> 1,601,664
  ushortT* wcomb=(ushortT*)(ws + 1601664);    // [1152][1024] bf16 -> 2,191,488
  float* xp    = ws + 2191488;                // [4096][1024] f32 -> 6,385,792
  ushortT* ubf = (ushortT*)(ws + 6385792);    // [4096][1024] bf16 -> 8,482,944
  ushortT* dtbf= (ushortT*)(ws + 8482944);    // [4096][1024] bf16 -> 10,580,096
  float* dbl32 = ws + 10580096;               // [4096][32]   f32 -> 10,711,168
  float* Pb    = ws + 10711168;               // 1,048,576 -> 11,759,744
  float* Qb    = ws + 11759744;               // 1,048,576 -> 12,808,320
  float* yv    = ws + 12808320;               // 8,192 -> 12,816,512
  float* xout  = ws + 12816512;               // 4,096 -> 12,820,608
  float* out   = (float*)d_out;

  k_stats <<<56, 64, 0, stream>>>(x_enc, mean, stdv, xn);
  k_embed <<<512, 512, 0, stream>>>(xn, x_mark, tconvw, tempw, (__hip_bfloat16*)xbf);
  k_prep  <<<1408, 256, 0, stream>>>(inprojw, dtw, xprojw, wbf, wcomb);
  k_inproj_mfma<<<dim3(8, 32), 256, 0, stream>>>(xbf, wbf, xp);
  k_dwconv<<<256, 1024, 0, stream>>>(xp, convw, convb, ubf);
  k_xdt_mfma<<<dim3(9, 32), 256, 0, stream>>>(ubf, wcomb, dtb, dtbf, dbl32);
  k_scan_chunk<<<dim3(NTC, 4, 8), 256, 0, stream>>>(dtbf, ubf, dbl32, alog, Pb, Qb);
  k_scan_combine<<<128, 64, 0, stream>>>(Pb, Qb, dbl32, ubf, xbf, wbf, dpar, yv);
  k_outproj<<<64, 256, 0, stream>>>(yv, outw, xout);
  k_head  <<<84, 256, 0, stream>>>(xout, headw, headb, mean, stdv, out);
}

// Round 9
// 114.178 us; speedup vs baseline: 3.2489x; 1.0875x over previous
//
#include <hip/hip_runtime.h>
#include <hip/hip_bf16.h>
#include <math.h>

#define BB 8
#define LL 512
#define CIN 7
#define MARKN 4
#define DM 512
#define DI 1024
#define DSN 16
#define NOUTC 672
#define NTC 8            // t-chunks in scan

typedef unsigned short ushortT;
typedef __attribute__((ext_vector_type(8))) short short8v;
typedef __attribute__((ext_vector_type(4))) float f32x4;

__device__ __forceinline__ float bf2f(ushortT u){ return __uint_as_float(((unsigned)u)<<16); }
__device__ __forceinline__ ushortT f2bf(float f){ __hip_bfloat16 h = __float2bfloat16(f); return *(ushortT*)&h; }

// ---------------- prep: wbf convert + W_dt + wcomb tail + stats (merged) ----------------
// blk 0-1023:    in_proj_w fp32 -> bf16 (1M elems)
// blk 1024-1279: W_dt[n][k] = sum_r dtw[n][r]*xpw[r][k] -> wcomb rows 0-1023 (bf16)
// blk 1280-1407: wcomb rows 1024-1055 = xpw rows 32-63 (bf16); rows 1056-1151 = 0
// blk 1408-1463: stats: mean/std over L per (b,c) + write normalized xn (64 active thr)
__global__ __launch_bounds__(256) void k_prep(const float* __restrict__ w_in,
    const float* __restrict__ dtw, const float* __restrict__ xpw,
    const float* __restrict__ xe,
    ushortT* __restrict__ wbf, ushortT* __restrict__ wcomb,
    float* __restrict__ mean, float* __restrict__ stdv, float* __restrict__ xn){
  int blk = blockIdx.x, tid = threadIdx.x;
  if(blk < 1024){
    int i = (blk*256 + tid)*4;
    float4 v = *(const float4*)(w_in + i);
    ushort4 pk; pk.x=f2bf(v.x); pk.y=f2bf(v.y); pk.z=f2bf(v.z); pk.w=f2bf(v.w);
    *(ushort4*)(wbf + i) = pk;
  } else if(blk < 1280){
    int n0 = (blk - 1024)*4;
    int k0 = tid*4;
    float acc[4][4] = {};
    for(int r=0;r<32;r++){
      float4 xv = *(const float4*)(xpw + r*1024 + k0);
      #pragma unroll
      for(int nn=0;nn<4;nn++){
        float wv = dtw[(n0+nn)*32 + r];
        acc[nn][0] += wv*xv.x; acc[nn][1] += wv*xv.y;
        acc[nn][2] += wv*xv.z; acc[nn][3] += wv*xv.w;
      }
    }
    #pragma unroll
    for(int nn=0;nn<4;nn++){
      ushort4 pk;
      pk.x=f2bf(acc[nn][0]); pk.y=f2bf(acc[nn][1]);
      pk.z=f2bf(acc[nn][2]); pk.w=f2bf(acc[nn][3]);
      *(ushort4*)(wcomb + (size_t)(n0+nn)*1024 + k0) = pk;
    }
  } else if(blk < 1408){
    int row = 1024 + (blk - 1280);     // 1024..1151
    int k0 = tid*4;
    ushort4 pk;
    if(row < 1056){
      float4 v = *(const float4*)(xpw + (size_t)(row-1024+32)*1024 + k0);
      pk.x=f2bf(v.x); pk.y=f2bf(v.y); pk.z=f2bf(v.z); pk.w=f2bf(v.w);
    } else { pk.x=0; pk.y=0; pk.z=0; pk.w=0; }
    *(ushort4*)(wcomb + (size_t)row*1024 + k0) = pk;
  } else if(tid < 64){
    int bc = blk - 1408;               // 0..55
    int b = bc / CIN, c = bc % CIN;
    int t = tid;
    const float* base = xe + (b*LL)*CIN + c;
    float v[8]; float s = 0.f;
    #pragma unroll
    for(int i=0;i<8;i++){ v[i] = base[(t + i*64)*CIN]; s += v[i]; }
    #pragma unroll
    for(int o=32;o>=1;o>>=1) s += __shfl_down(s, o);
    float m = __shfl(s, 0) * (1.0f/LL);
    float vs = 0.f;
    #pragma unroll
    for(int i=0;i<8;i++){ float dv = v[i]-m; vs += dv*dv; }
    #pragma unroll
    for(int o=32;o>=1;o>>=1) vs += __shfl_down(vs, o);
    float var = __shfl(vs, 0) * (1.0f/LL);
    float sd = sqrtf(var + 1e-5f);
    float inv = 1.0f / sd;
    if(t == 0){ mean[bc] = m; stdv[bc] = sd; }
    float* xnb = xn + (b*LL)*CIN + c;
    #pragma unroll
    for(int i=0;i<8;i++) xnb[(t + i*64)*CIN] = (v[i]-m)*inv;
  }
}

// ---------------- embedding: token conv (wrap pad) + temporal proj + PE -> bf16 x ----------------
__global__ __launch_bounds__(512) void k_embed(const float* __restrict__ xn,
    const float* __restrict__ xmark, const float* __restrict__ tw,
    const float* __restrict__ tpw, __hip_bfloat16* __restrict__ xo){
  __shared__ float sw[DM*21];          // token_conv_w staged (43KB)
  __shared__ float sxr[10][CIN];       // xn rows l0-1 .. l0+8 (wrap)
  __shared__ float smr[8][MARKN];
  int blk = blockIdx.x;                // 512 = 8 b * 64 chunks
  int b = blk >> 6;
  int l0 = (blk & 63) << 3;            // 8 l per block
  int tid = threadIdx.x;
  for(int i=tid; i<DM*21; i+=512) sw[i] = tw[i];
  if(tid < 70){
    int r = tid / CIN, c = tid % CIN;
    int ls = (l0 - 1 + r + LL) % LL;
    sxr[r][c] = xn[(b*LL + ls)*CIN + c];
  } else if(tid >= 128 && tid < 160){
    int i2 = tid - 128; int r = i2 >> 2, m = i2 & 3;
    smr[r][m] = xmark[(b*LL + l0 + r)*MARKN + m];
  }
  __syncthreads();
  int d = tid;
  float wv[21];
  #pragma unroll
  for(int i=0;i<21;i++) wv[i] = sw[d*21 + i];
  float tv[4];
  #pragma unroll
  for(int m=0;m<4;m++) tv[m] = tpw[d*MARKN + m];
  float divv = expf((float)(2*(d>>1)) * (-0.0179889460390159843f));
  bool isodd = (d & 1) != 0;
  #pragma unroll
  for(int ll=0; ll<8; ll++){
    float acc = 0.f;
    #pragma unroll
    for(int c=0;c<CIN;c++){
      #pragma unroll
      for(int k=0;k<3;k++) acc += sxr[ll+k][c] * wv[c*3+k];
    }
    #pragma unroll
    for(int m=0;m<4;m++) acc += smr[ll][m] * tv[m];
    float ang = (float)(l0+ll) * divv;
    acc += isodd ? cosf(ang) : sinf(ang);
    xo[(size_t)(b*LL + l0 + ll)*DM + d] = __float2bfloat16(acc);
  }
}

// ---------------- in_proj MFMA GEMM: xpbf[4096][1024](bf16) = Xbf @ Wbf[0:1024]^T ----------------
__global__ __launch_bounds__(256) void k_inproj_mfma(const ushortT* __restrict__ A,
    const ushortT* __restrict__ Bw, ushortT* __restrict__ C){
  __shared__ ushortT Asl[2][128*64];
  __shared__ ushortT Bsl[2][128*64];
  int tid = threadIdx.x;
  int w = tid >> 6, l = tid & 63;
  int m0 = blockIdx.y * 128, n0 = blockIdx.x * 128;
  int wr = w >> 1, wc = w & 1;
  f32x4 acc[4][4] = {};
  int srow = l >> 3;
  int scolswz = ((l & 7) * 16) ^ (srow << 4);

#define IP_STAGE(bufi, kt) do{ \
    _Pragma("unroll") \
    for(int i=0;i<4;i++){ \
      int r0 = w*32 + i*8; \
      int r = r0 + srow; \
      const ushortT* gA = A + (size_t)(m0 + r)*512 + (kt)*64 + (scolswz>>1); \
      const ushortT* gB = Bw + (size_t)(n0 + r)*512 + (kt)*64 + (scolswz>>1); \
      __builtin_amdgcn_global_load_lds( \
        (const __attribute__((address_space(1))) unsigned int*)(const void*)gA, \
        (__attribute__((address_space(3))) unsigned int*)(void*)(Asl[bufi] + r0*64), 16, 0, 0); \
      __builtin_amdgcn_global_load_lds( \
        (const __attribute__((address_space(1))) unsigned int*)(const void*)gB, \
        (__attribute__((address_space(3))) unsigned int*)(void*)(Bsl[bufi] + r0*64), 16, 0, 0); \
    } }while(0)

  IP_STAGE(0, 0);
  __syncthreads();
  int cur = 0;
  for(int kt = 0; kt < 8; ++kt){
    if(kt < 7) IP_STAGE(cur^1, kt+1);
    #pragma unroll
    for(int kk=0;kk<2;kk++){
      short8v af[4], bfr[4];
      int cb = kk*64 + (l>>4)*16;
      #pragma unroll
      for(int mf=0;mf<4;mf++){
        int ar = wr*64 + mf*16 + (l&15);
        af[mf] = *(const short8v*)(Asl[cur] + ar*64 + ((cb ^ ((ar&7)<<4))>>1));
      }
      #pragma unroll
      for(int nf=0;nf<4;nf++){
        int br = wc*64 + nf*16 + (l&15);
        bfr[nf] = *(const short8v*)(Bsl[cur] + br*64 + ((cb ^ ((br&7)<<4))>>1));
      }
      #pragma unroll
      for(int mf=0;mf<4;mf++)
        #pragma unroll
        for(int nf=0;nf<4;nf++)
          acc[mf][nf] = __builtin_amdgcn_mfma_f32_16x16x32_bf16(af[mf], bfr[nf], acc[mf][nf], 0, 0, 0);
    }
    __syncthreads();
    cur ^= 1;
  }
#undef IP_STAGE
  #pragma unroll
  for(int mf=0;mf<4;mf++){
    int rbase = m0 + wr*64 + mf*16 + (l>>4)*4;
    #pragma unroll
    for(int nf=0;nf<4;nf++){
      int col = n0 + wc*64 + nf*16 + (l&15);
      #pragma unroll
      for(int r=0;r<4;r++)
        C[(size_t)(rbase+r)*1024 + col] = f2bf(acc[mf][nf][r]);
    }
  }
}

// ---------------- causal depthwise conv (D_CONV=4) + silu: xpbf(bf16) -> ubf (bf16) ----------------
__global__ __launch_bounds__(1024) void k_dwconv(const ushortT* __restrict__ xpbf,
    const float* __restrict__ cw, const float* __restrict__ cb,
    ushortT* __restrict__ ubf){
  int blk = blockIdx.x;                 // 256 = 8 b * 32 lchunks
  int b = blk >> 5, l0 = (blk & 31) * 16;
  int d = threadIdx.x;                  // 1024
  const float4 w4 = *(const float4*)(cw + d*4);
  float bias = cb[d];
  const ushortT* base = xpbf + (size_t)(b*LL + l0)*1024 + d;
  float x0=0.f, x1=0.f, x2=0.f;
  if(l0 > 0){
    x0 = bf2f(base[-3*1024]); x1 = bf2f(base[-2*1024]); x2 = bf2f(base[-1*1024]);
  }
  #pragma unroll
  for(int ll=0; ll<16; ++ll){
    float x3 = bf2f(base[(size_t)ll*1024]);
    float acc = bias + x0*w4.x + x1*w4.y + x2*w4.z + x3*w4.w;
    float s = acc / (1.f + __expf(-acc));
    ubf[(size_t)(b*LL + l0 + ll)*1024 + d] = f2bf(s);
    x0 = x1; x1 = x2; x2 = x3;
  }
}

// ---------------- combined x_proj+dt_proj MFMA: [4096][1152] = ubf @ wcomb^T ----------------
// cols 0-1023 -> dt = softplus(.+dtb) stored bf16; cols 1024-1055 -> dbl32 (B|C); rest discard
__global__ __launch_bounds__(256) void k_xdt_mfma(const ushortT* __restrict__ A,
    const ushortT* __restrict__ Bw, const float* __restrict__ dtb,
    ushortT* __restrict__ dtbf, float* __restrict__ dbl32){
  __shared__ ushortT Asl[2][128*64];
  __shared__ ushortT Bsl[2][128*64];
  int tid = threadIdx.x;
  int w = tid >> 6, l = tid & 63;
  int m0 = blockIdx.y * 128, n0 = blockIdx.x * 128;
  int wr = w >> 1, wc = w & 1;
  f32x4 acc[4][4] = {};
  int srow = l >> 3;
  int scolswz = ((l & 7) * 16) ^ (srow << 4);

#define XD_STAGE(bufi, kt) do{ \
    _Pragma("unroll") \
    for(int i=0;i<4;i++){ \
      int r0 = w*32 + i*8; \
      int r = r0 + srow; \
      const ushortT* gA = A + (size_t)(m0 + r)*1024 + (kt)*64 + (scolswz>>1); \
      const ushortT* gB = Bw + (size_t)(n0 + r)*1024 + (kt)*64 + (scolswz>>1); \
      __builtin_amdgcn_global_load_lds( \
        (const __attribute__((address_space(1))) unsigned int*)(const void*)gA, \
        (__attribute__((address_space(3))) unsigned int*)(void*)(Asl[bufi] + r0*64), 16, 0, 0); \
      __builtin_amdgcn_global_load_lds( \
        (const __attribute__((address_space(1))) unsigned int*)(const void*)gB, \
        (__attribute__((address_space(3))) unsigned int*)(void*)(Bsl[bufi] + r0*64), 16, 0, 0); \
    } }while(0)

  XD_STAGE(0, 0);
  __syncthreads();
  int cur = 0;
  for(int kt = 0; kt < 16; ++kt){
    if(kt < 15) XD_STAGE(cur^1, kt+1);
    #pragma unroll
    for(int kk=0;kk<2;kk++){
      short8v af[4], bfr[4];
      int cb = kk*64 + (l>>4)*16;
      #pragma unroll
      for(int mf=0;mf<4;mf++){
        int ar = wr*64 + mf*16 + (l&15);
        af[mf] = *(const short8v*)(Asl[cur] + ar*64 + ((cb ^ ((ar&7)<<4))>>1));
      }
      #pragma unroll
      for(int nf=0;nf<4;nf++){
        int br = wc*64 + nf*16 + (l&15);
        bfr[nf] = *(const short8v*)(Bsl[cur] + br*64 + ((cb ^ ((br&7)<<4))>>1));
      }
      #pragma unroll
      for(int mf=0;mf<4;mf++)
        #pragma unroll
        for(int nf=0;nf<4;nf++)
          acc[mf][nf] = __builtin_amdgcn_mfma_f32_16x16x32_bf16(af[mf], bfr[nf], acc[mf][nf], 0, 0, 0);
    }
    __syncthreads();
    cur ^= 1;
  }
#undef XD_STAGE
  #pragma unroll
  for(int mf=0;mf<4;mf++){
    int rbase = m0 + wr*64 + mf*16 + (l>>4)*4;
    #pragma unroll
    for(int nf=0;nf<4;nf++){
      int col = n0 + wc*64 + nf*16 + (l&15);
      if(col < 1024){
        float bb = dtb[col];
        #pragma unroll
        for(int r=0;r<4;r++){
          float v = acc[mf][nf][r] + bb;
          float sp = (v > 20.f) ? v : __logf(1.f + __expf(v));
          dtbf[(size_t)(rbase+r)*1024 + col] = f2bf(sp);
        }
      } else if(col < 1056){
        #pragma unroll
        for(int r=0;r<4;r++)
          dbl32[(size_t)(rbase+r)*32 + (col-1024)] = acc[mf][nf][r];
      }
    }
  }
}

// ---------------- scan chunk: per (b,d,tchunk) compute P,Q s.t. h_out = P*h_in + Q ----------------
// P/Q stored as float4 [(tc*8+b)*4 + n4][d] for coalesced write/read (d fastest)
__global__ __launch_bounds__(256) void k_scan_chunk(const ushortT* __restrict__ dtbf,
    const ushortT* __restrict__ ubf, const float* __restrict__ dbl32,
    const float* __restrict__ alog, float4* __restrict__ P4, float4* __restrict__ Q4){
  int tc = blockIdx.x;                 // 8 t-chunks of 64
  int dgrp = blockIdx.y;               // 4 groups of 256 d
  int b = blockIdx.z;                  // 8
  int tid = threadIdx.x;               // 256
  int d = dgrp*256 + tid;
  __shared__ float sB[64][16];
  for(int i=tid; i<1024; i+=256){
    int t = i >> 4, n = i & 15;
    sB[t][n] = dbl32[(size_t)(b*LL + tc*64 + t)*32 + n];
  }
  float Ad[16];
  {
    float4 a0 = *(const float4*)(alog + d*16);
    float4 a1 = *(const float4*)(alog + d*16 + 4);
    float4 a2 = *(const float4*)(alog + d*16 + 8);
    float4 a3 = *(const float4*)(alog + d*16 + 12);
    Ad[0]=-__expf(a0.x); Ad[1]=-__expf(a0.y); Ad[2]=-__expf(a0.z); Ad[3]=-__expf(a0.w);
    Ad[4]=-__expf(a1.x); Ad[5]=-__expf(a1.y); Ad[6]=-__expf(a1.z); Ad[7]=-__expf(a1.w);
    Ad[8]=-__expf(a2.x); Ad[9]=-__expf(a2.y); Ad[10]=-__expf(a2.z); Ad[11]=-__expf(a2.w);
    Ad[12]=-__expf(a3.x); Ad[13]=-__expf(a3.y); Ad[14]=-__expf(a3.z); Ad[15]=-__expf(a3.w);
  }
  __syncthreads();
  float h[16];
  #pragma unroll
  for(int n=0;n<16;n++) h[n] = 0.f;
  float Ss = 0.f;
  const ushortT* dtp = dtbf + (size_t)(b*LL + tc*64)*1024 + d;
  const ushortT* up  = ubf  + (size_t)(b*LL + tc*64)*1024 + d;
  #pragma unroll 4
  for(int t=0;t<64;t++){
    float dtv = bf2f(dtp[(size_t)t*1024]);
    float uv  = bf2f(up [(size_t)t*1024]);
    float wt = dtv * uv;
    Ss += dtv;
    float4 B0 = *(const float4*)&sB[t][0];
    float4 B1 = *(const float4*)&sB[t][4];
    float4 B2 = *(const float4*)&sB[t][8];
    float4 B3 = *(const float4*)&sB[t][12];
    float Bv[16] = {B0.x,B0.y,B0.z,B0.w, B1.x,B1.y,B1.z,B1.w,
                    B2.x,B2.y,B2.z,B2.w, B3.x,B3.y,B3.z,B3.w};
    #pragma unroll
    for(int n=0;n<16;n++){
      float e = __expf(dtv * Ad[n]);
      h[n] = h[n]*e + wt*Bv[n];
    }
  }
  size_t base4 = (size_t)(tc*8 + b)*4*1024 + d;
  #pragma unroll
  for(int n4=0;n4<4;n4++){
    Q4[base4 + n4*1024] = make_float4(h[n4*4], h[n4*4+1], h[n4*4+2], h[n4*4+3]);
    P4[base4 + n4*1024] = make_float4(__expf(Ss*Ad[n4*4]), __expf(Ss*Ad[n4*4+1]),
                                      __expf(Ss*Ad[n4*4+2]), __expf(Ss*Ad[n4*4+3]));
  }
}

// ---------------- combine chunks + z_last dot + C-dot + gating -> yv[b][d] ----------------
// 128 blocks x 64 thr; gid: b = gid>>10, d = gid&1023 (d fastest -> coalesced P/Q)
__global__ __launch_bounds__(64) void k_scan_combine(const float4* __restrict__ P4,
    const float4* __restrict__ Q4, const float* __restrict__ dbl32,
    const ushortT* __restrict__ ubf, const ushortT* __restrict__ xbf,
    const ushortT* __restrict__ wbf, const float* __restrict__ Dp,
    float* __restrict__ yv){
  int gid = blockIdx.x*64 + threadIdx.x;   // 8192
  int b = gid >> 10, d = gid & 1023;
  // z_last: dot(xbf[b,511,:], wbf[1024+d,:]) over K=512
  const ushortT* xr = xbf + (size_t)(b*LL + LL-1)*512;
  const ushortT* wr = wbf + (size_t)(1024 + d)*512;
  float zl = 0.f;
  for(int k=0;k<512;k+=8){
    short8v xv = *(const short8v*)(xr + k);
    short8v wv = *(const short8v*)(wr + k);
    #pragma unroll
    for(int j=0;j<8;j++) zl += bf2f((ushortT)xv[j])*bf2f((ushortT)wv[j]);
  }
  float h[16];
  #pragma unroll
  for(int n=0;n<16;n++) h[n] = 0.f;
  #pragma unroll
  for(int c=0;c<NTC;c++){
    size_t base4 = (size_t)(c*8 + b)*4*1024 + d;
    #pragma unroll
    for(int n4=0;n4<4;n4++){
      float4 pv = P4[base4 + n4*1024];
      float4 qv = Q4[base4 + n4*1024];
      h[n4*4+0] = pv.x*h[n4*4+0] + qv.x;
      h[n4*4+1] = pv.y*h[n4*4+1] + qv.y;
      h[n4*4+2] = pv.z*h[n4*4+2] + qv.z;
      h[n4*4+3] = pv.w*h[n4*4+3] + qv.w;
    }
  }
  const float* Crow = dbl32 + (size_t)(b*LL + LL-1)*32 + 16;
  float y = 0.f;
  #pragma unroll
  for(int n=0;n<16;n++) y += Crow[n]*h[n];
  float ul = bf2f(ubf[(size_t)(b*LL + LL-1)*1024 + d]);
  float sz = zl / (1.f + __expf(-zl));
  yv[b*1024 + d] = (y + ul*Dp[d]) * sz;
}

// ---------------- out_proj (last step only): xout[8][512] ----------------
__global__ __launch_bounds__(256) void k_outproj(const float* __restrict__ yv,
    const float* __restrict__ W, float* __restrict__ xout){
  int tid = threadIdx.x;
  int j = blockIdx.x*8 + (tid>>5);     // 64 blocks -> 512 outputs
  int ks = tid & 31;
  float a[8] = {};
  #pragma unroll
  for(int t=0;t<8;t++){
    int k = ks*4 + t*128;
    float4 wv = *(const float4*)(W + (size_t)j*1024 + k);
    #pragma unroll
    for(int b=0;b<8;b++){
      float4 xv = *(const float4*)(yv + b*1024 + k);
      a[b] += xv.x*wv.x + xv.y*wv.y + xv.z*wv.z + xv.w*wv.w;
    }
  }
  #pragma unroll
  for(int b=0;b<8;b++){
    #pragma unroll
    for(int o=16;o>=1;o>>=1) a[b] += __shfl_xor(a[b], o);
  }
  if(ks==0){
    #pragma unroll
    for(int b=0;b<8;b++) xout[b*512 + j] = a[b];
  }
}

// ---------------- head + denorm -> out[8][96][7] ----------------
__global__ __launch_bounds__(256) void k_head(const float* __restrict__ xout,
    const float* __restrict__ W, const float* __restrict__ hb,
    const float* __restrict__ mean, const float* __restrict__ stdv,
    float* __restrict__ out){
  int tid = threadIdx.x;
  int o = blockIdx.x*8 + (tid>>5);     // 84 blocks -> 672 outputs
  int ks = tid & 31;
  float a[8] = {};
  #pragma unroll
  for(int t=0;t<4;t++){
    int k = ks*4 + t*128;
    float4 wv = *(const float4*)(W + (size_t)o*512 + k);
    #pragma unroll
    for(int b=0;b<8;b++){
      float4 xv = *(const float4*)(xout + b*512 + k);
      a[b] += xv.x*wv.x + xv.y*wv.y + xv.z*wv.z + xv.w*wv.w;
    }
  }
  #pragma unroll
  for(int b=0;b<8;b++){
    #pragma unroll
    for(int oo=16;oo>=1;oo>>=1) a[b] += __shfl_xor(a[b], oo);
  }
  if(ks==0){
    int c = o % 7;
    #pragma unroll
    for(int b=0;b<8;b++){
      float v = a[b] + hb[o];
      out[b*NOUTC + o] = v * stdv[b*CIN + c] + mean[b*CIN + c];
    }
  }
}

extern "C" void kernel_launch(void* const* d_in, const int* in_sizes, int n_in,
                              void* d_out, int out_size, void* d_ws, size_t ws_size,
                              hipStream_t stream) {
  const float* x_enc   = (const float*)d_in[0];
  const float* x_mark  = (const float*)d_in[1];
  const float* tconvw  = (const float*)d_in[4];
  const float* tempw   = (const float*)d_in[5];
  const float* inprojw = (const float*)d_in[6];
  const float* convw   = (const float*)d_in[7];
  const float* convb   = (const float*)d_in[8];
  const float* xprojw  = (const float*)d_in[9];
  const float* dtw     = (const float*)d_in[10];
  const float* dtb     = (const float*)d_in[11];
  const float* alog    = (const float*)d_in[12];
  const float* dpar    = (const float*)d_in[13];
  const float* outw    = (const float*)d_in[14];
  const float* headw   = (const float*)d_in[15];
  const float* headb   = (const float*)d_in[16];

  float* ws    = (float*)d_ws;
  float* mean  = ws;                          // 64
  float* stdv  = ws + 64;                     // 64
  float* xn    = ws + 128;                    // 28,672 -> 28,800
  ushortT* xbf = (ushortT*)(ws + 28800);      // [4096][512]  bf16 -> 1,077,376
  ushortT* wbf = (ushortT*)(ws + 1077376);    // [2048][512]  bf16 -> 1,601,664
  ushortT* wcomb=(ushortT*)(ws + 1601664);    // [1152][1024] bf16 -> 2,191,488
  ushortT* xpbf= (ushortT*)(ws + 2191488);    // [4096][1024] bf16 -> 4,288,640
  ushortT* ubf = (ushortT*)(ws + 4288640);    // [4096][1024] bf16 -> 6,385,792
  ushortT* dtbf= (ushortT*)(ws + 6385792);    // [4096][1024] bf16 -> 8,482,944
  float* dbl32 = ws + 8482944;                // [4096][32]   f32 -> 8,614,016
  float4* P4   = (float4*)(ws + 8614016);     // 262,144 float4 -> 9,662,592
  float4* Q4   = (float4*)(ws + 9662592);     // 262,144 float4 -> 10,711,168
  float* yv    = ws + 10711168;               // 8,192 -> 10,719,360
  float* xout  = ws + 10719360;               // 4,096 -> 10,723,456
  float* out   = (float*)d_out;

  k_prep  <<<1464, 256, 0, stream>>>(inprojw, dtw, xprojw, x_enc, wbf, wcomb, mean, stdv, xn);
  k_embed <<<512, 512, 0, stream>>>(xn, x_mark, tconvw, tempw, (__hip_bfloat16*)xbf);
  k_inproj_mfma<<<dim3(8, 32), 256, 0, stream>>>(xbf, wbf, xpbf);
  k_dwconv<<<256, 1024, 0, stream>>>(xpbf, convw, convb, ubf);
  k_xdt_mfma<<<dim3(9, 32), 256, 0, stream>>>(ubf, wcomb, dtb, dtbf, dbl32);
  k_scan_chunk<<<dim3(NTC, 4, 8), 256, 0, stream>>>(dtbf, ubf, dbl32, alog, P4, Q4);
  k_scan_combine<<<128, 64, 0, stream>>>(P4, Q4, dbl32, ubf, xbf, wbf, dpar, yv);
  k_outproj<<<64, 256, 0, stream>>>(yv, outw, xout);
  k_head  <<<84, 256, 0, stream>>>(xout, headw, headb, mean, stdv, out);
}

// Round 12
// 102.517 us; speedup vs baseline: 3.6185x; 1.1137x over previous
//
#include <hip/hip_runtime.h>
#include <hip/hip_bf16.h>
#include <math.h>

#define BB 8
#define LL 512
#define CIN 7
#define MARKN 4
#define DM 512
#define DI 1024
#define DSN 16
#define NOUTC 672
#define NTC 8            // t-chunks in scan

typedef unsigned short ushortT;
typedef __attribute__((ext_vector_type(8))) short short8v;
typedef __attribute__((ext_vector_type(4))) float f32x4;

__device__ __forceinline__ float bf2f(ushortT u){ return __uint_as_float(((unsigned)u)<<16); }
__device__ __forceinline__ ushortT f2bf(float f){ __hip_bfloat16 h = __float2bfloat16(f); return *(ushortT*)&h; }

// ---------------- prep: wbf convert + xpw convert + stats (merged) ----------------
// blk 0-1023:    in_proj_w fp32 -> bf16 (1,048,576 elems)
// blk 1024-1087: x_proj_w fp32 -> bf16 (65,536 elems)
// blk 1088-1143: stats: mean/std over L per (b,c) + write normalized xn (64 active thr)
__global__ __launch_bounds__(256) void k_prep(const float* __restrict__ w_in,
    const float* __restrict__ xpw, const float* __restrict__ xe,
    ushortT* __restrict__ wbf, ushortT* __restrict__ xpwbf,
    float* __restrict__ mean, float* __restrict__ stdv, float* __restrict__ xn){
  int blk = blockIdx.x, tid = threadIdx.x;
  if(blk < 1024){
    int i = (blk*256 + tid)*4;
    float4 v = *(const float4*)(w_in + i);
    ushort4 pk; pk.x=f2bf(v.x); pk.y=f2bf(v.y); pk.z=f2bf(v.z); pk.w=f2bf(v.w);
    *(ushort4*)(wbf + i) = pk;
  } else if(blk < 1088){
    int i = ((blk-1024)*256 + tid)*4;
    float4 v = *(const float4*)(xpw + i);
    ushort4 pk; pk.x=f2bf(v.x); pk.y=f2bf(v.y); pk.z=f2bf(v.z); pk.w=f2bf(v.w);
    *(ushort4*)(xpwbf + i) = pk;
  } else if(tid < 64){
    int bc = blk - 1088;               // 0..55
    int b = bc / CIN, c = bc % CIN;
    int t = tid;
    const float* base = xe + (b*LL)*CIN + c;
    float v[8]; float s = 0.f;
    #pragma unroll
    for(int i=0;i<8;i++){ v[i] = base[(t + i*64)*CIN]; s += v[i]; }
    #pragma unroll
    for(int o=32;o>=1;o>>=1) s += __shfl_down(s, o);
    float m = __shfl(s, 0) * (1.0f/LL);
    float vs = 0.f;
    #pragma unroll
    for(int i=0;i<8;i++){ float dv = v[i]-m; vs += dv*dv; }
    #pragma unroll
    for(int o=32;o>=1;o>>=1) vs += __shfl_down(vs, o);
    float var = __shfl(vs, 0) * (1.0f/LL);
    float sd = sqrtf(var + 1e-5f);
    float inv = 1.0f / sd;
    if(t == 0){ mean[bc] = m; stdv[bc] = sd; }
    float* xnb = xn + (b*LL)*CIN + c;
    #pragma unroll
    for(int i=0;i<8;i++) xnb[(t + i*64)*CIN] = (v[i]-m)*inv;
  }
}

// ---------------- embedding: token conv (wrap pad) + temporal proj + PE -> bf16 x ----------------
__global__ __launch_bounds__(512) void k_embed(const float* __restrict__ xn,
    const float* __restrict__ xmark, const float* __restrict__ tw,
    const float* __restrict__ tpw, __hip_bfloat16* __restrict__ xo){
  __shared__ float sw[DM*21];          // token_conv_w staged (43KB)
  __shared__ float sxr[10][CIN];       // xn rows l0-1 .. l0+8 (wrap)
  __shared__ float smr[8][MARKN];
  int blk = blockIdx.x;                // 512 = 8 b * 64 chunks
  int b = blk >> 6;
  int l0 = (blk & 63) << 3;            // 8 l per block
  int tid = threadIdx.x;
  for(int i=tid; i<DM*21; i+=512) sw[i] = tw[i];
  if(tid < 70){
    int r = tid / CIN, c = tid % CIN;
    int ls = (l0 - 1 + r + LL) % LL;
    sxr[r][c] = xn[(b*LL + ls)*CIN + c];
  } else if(tid >= 128 && tid < 160){
    int i2 = tid - 128; int r = i2 >> 2, m = i2 & 3;
    smr[r][m] = xmark[(b*LL + l0 + r)*MARKN + m];
  }
  __syncthreads();
  int d = tid;
  float wv[21];
  #pragma unroll
  for(int i=0;i<21;i++) wv[i] = sw[d*21 + i];
  float tv[4];
  #pragma unroll
  for(int m=0;m<4;m++) tv[m] = tpw[d*MARKN + m];
  float divv = expf((float)(2*(d>>1)) * (-0.0179889460390159843f));
  bool isodd = (d & 1) != 0;
  #pragma unroll
  for(int ll=0; ll<8; ll++){
    float acc = 0.f;
    #pragma unroll
    for(int c=0;c<CIN;c++){
      #pragma unroll
      for(int k=0;k<3;k++) acc += sxr[ll+k][c] * wv[c*3+k];
    }
    #pragma unroll
    for(int m=0;m<4;m++) acc += smr[ll][m] * tv[m];
    float ang = (float)(l0+ll) * divv;
    acc += isodd ? cosf(ang) : sinf(ang);
    xo[(size_t)(b*LL + l0 + ll)*DM + d] = __float2bfloat16(acc);
  }
}

// ---------------- in_proj MFMA GEMM: xpbf[4096][1024](bf16) = Xbf @ Wbf[0:1024]^T ----------------
__global__ __launch_bounds__(256) void k_inproj_mfma(const ushortT* __restrict__ A,
    const ushortT* __restrict__ Bw, ushortT* __restrict__ C){
  __shared__ ushortT Asl[2][128*64];
  __shared__ ushortT Bsl[2][128*64];
  int tid = threadIdx.x;
  int w = tid >> 6, l = tid & 63;
  int m0 = blockIdx.y * 128, n0 = blockIdx.x * 128;
  int wr = w >> 1, wc = w & 1;
  f32x4 acc[4][4] = {};
  int srow = l >> 3;
  int scolswz = ((l & 7) * 16) ^ (srow << 4);

#define IP_STAGE(bufi, kt) do{ \
    _Pragma("unroll") \
    for(int i=0;i<4;i++){ \
      int r0 = w*32 + i*8; \
      int r = r0 + srow; \
      const ushortT* gA = A + (size_t)(m0 + r)*512 + (kt)*64 + (scolswz>>1); \
      const ushortT* gB = Bw + (size_t)(n0 + r)*512 + (kt)*64 + (scolswz>>1); \
      __builtin_amdgcn_global_load_lds( \
        (const __attribute__((address_space(1))) unsigned int*)(const void*)gA, \
        (__attribute__((address_space(3))) unsigned int*)(void*)(Asl[bufi] + r0*64), 16, 0, 0); \
      __builtin_amdgcn_global_load_lds( \
        (const __attribute__((address_space(1))) unsigned int*)(const void*)gB, \
        (__attribute__((address_space(3))) unsigned int*)(void*)(Bsl[bufi] + r0*64), 16, 0, 0); \
    } }while(0)

  IP_STAGE(0, 0);
  __syncthreads();
  int cur = 0;
  for(int kt = 0; kt < 8; ++kt){
    if(kt < 7) IP_STAGE(cur^1, kt+1);
    #pragma unroll
    for(int kk=0;kk<2;kk++){
      short8v af[4], bfr[4];
      int cb = kk*64 + (l>>4)*16;
      #pragma unroll
      for(int mf=0;mf<4;mf++){
        int ar = wr*64 + mf*16 + (l&15);
        af[mf] = *(const short8v*)(Asl[cur] + ar*64 + ((cb ^ ((ar&7)<<4))>>1));
      }
      #pragma unroll
      for(int nf=0;nf<4;nf++){
        int br = wc*64 + nf*16 + (l&15);
        bfr[nf] = *(const short8v*)(Bsl[cur] + br*64 + ((cb ^ ((br&7)<<4))>>1));
      }
      #pragma unroll
      for(int mf=0;mf<4;mf++)
        #pragma unroll
        for(int nf=0;nf<4;nf++)
          acc[mf][nf] = __builtin_amdgcn_mfma_f32_16x16x32_bf16(af[mf], bfr[nf], acc[mf][nf], 0, 0, 0);
    }
    __syncthreads();
    cur ^= 1;
  }
#undef IP_STAGE
  #pragma unroll
  for(int mf=0;mf<4;mf++){
    int rbase = m0 + wr*64 + mf*16 + (l>>4)*4;
    #pragma unroll
    for(int nf=0;nf<4;nf++){
      int col = n0 + wc*64 + nf*16 + (l&15);
      #pragma unroll
      for(int r=0;r<4;r++)
        C[(size_t)(rbase+r)*1024 + col] = f2bf(acc[mf][nf][r]);
    }
  }
}

// ---------------- causal depthwise conv (D_CONV=4) + silu: xpbf(bf16) -> ubf (bf16) ----------------
__global__ __launch_bounds__(1024) void k_dwconv(const ushortT* __restrict__ xpbf,
    const float* __restrict__ cw, const float* __restrict__ cb,
    ushortT* __restrict__ ubf){
  int blk = blockIdx.x;                 // 256 = 8 b * 32 lchunks
  int b = blk >> 5, l0 = (blk & 31) * 16;
  int d = threadIdx.x;                  // 1024
  const float4 w4 = *(const float4*)(cw + d*4);
  float bias = cb[d];
  const ushortT* base = xpbf + (size_t)(b*LL + l0)*1024 + d;
  float x0=0.f, x1=0.f, x2=0.f;
  if(l0 > 0){
    x0 = bf2f(base[-3*1024]); x1 = bf2f(base[-2*1024]); x2 = bf2f(base[-1*1024]);
  }
  #pragma unroll
  for(int ll=0; ll<16; ++ll){
    float x3 = bf2f(base[(size_t)ll*1024]);
    float acc = bias + x0*w4.x + x1*w4.y + x2*w4.z + x3*w4.w;
    float s = acc / (1.f + __expf(-acc));
    ubf[(size_t)(b*LL + l0 + ll)*1024 + d] = f2bf(s);
    x0 = x1; x1 = x2; x2 = x3;
  }
}

// ---------------- x_proj MFMA GEMM: dbl[4096][64] = ubf[4096][1024] @ xpwbf[64][1024]^T ----------------
// 64x64 tile, BK=64, 4 waves (each 16 rows x 64 cols), 2-phase double-buffered LDS
__global__ __launch_bounds__(256) void k_xproj_mfma(const ushortT* __restrict__ A,
    const ushortT* __restrict__ Bw, float* __restrict__ C){
  __shared__ ushortT Asl[2][64*64];
  __shared__ ushortT Bsl[2][64*64];
  int tid = threadIdx.x;
  int w = tid >> 6, l = tid & 63;
  int m0 = blockIdx.x * 64;
  f32x4 acc[4] = {};
  int srow = l >> 3;
  int scol = ((l & 7) * 16) ^ (srow << 4);   // pre-swizzled source byte col

#define XP_STAGE(bufi, kt) do{ \
    _Pragma("unroll") \
    for(int i=0;i<2;i++){ \
      int r0 = w*16 + i*8; \
      int r = r0 + srow; \
      const ushortT* gA = A + (size_t)(m0 + r)*1024 + (kt)*64 + (scol>>1); \
      const ushortT* gB = Bw + (size_t)r*1024 + (kt)*64 + (scol>>1); \
      __builtin_amdgcn_global_load_lds( \
        (const __attribute__((address_space(1))) unsigned int*)(const void*)gA, \
        (__attribute__((address_space(3))) unsigned int*)(void*)(Asl[bufi] + r0*64), 16, 0, 0); \
      __builtin_amdgcn_global_load_lds( \
        (const __attribute__((address_space(1))) unsigned int*)(const void*)gB, \
        (__attribute__((address_space(3))) unsigned int*)(void*)(Bsl[bufi] + r0*64), 16, 0, 0); \
    } }while(0)

  XP_STAGE(0, 0);
  __syncthreads();
  int cur = 0;
  for(int kt = 0; kt < 16; ++kt){
    if(kt < 15) XP_STAGE(cur^1, kt+1);
    #pragma unroll
    for(int kk=0;kk<2;kk++){
      int cb = kk*64 + (l>>4)*16;
      int ar = w*16 + (l&15);
      short8v af = *(const short8v*)(Asl[cur] + ar*64 + ((cb ^ ((ar&7)<<4))>>1));
      #pragma unroll
      for(int nf=0;nf<4;nf++){
        int br = nf*16 + (l&15);
        short8v bfv = *(const short8v*)(Bsl[cur] + br*64 + ((cb ^ ((br&7)<<4))>>1));
        acc[nf] = __builtin_amdgcn_mfma_f32_16x16x32_bf16(af, bfv, acc[nf], 0, 0, 0);
      }
    }
    __syncthreads();
    cur ^= 1;
  }
#undef XP_STAGE
  int rbase = m0 + w*16 + (l>>4)*4;
  #pragma unroll
  for(int nf=0;nf<4;nf++){
    int col = nf*16 + (l&15);
    #pragma unroll
    for(int r=0;r<4;r++)
      C[(size_t)(rbase+r)*64 + col] = acc[nf][r];
  }
}

// ---------------- scan chunk (dt fused): per (b,d,tchunk) compute P,Q ----------------
// dbl rows staged in LDS (broadcast reads); dt = softplus(dot32(dt_low, dtw[d]) + dtb[d]) on the fly
// P/Q stored as float4 [(tc*8+b)*4 + n4][d] for coalesced write/read (d fastest)
__global__ __launch_bounds__(256) void k_scan_chunk(const float* __restrict__ dbl,
    const ushortT* __restrict__ ubf, const float* __restrict__ dtw,
    const float* __restrict__ dtb, const float* __restrict__ alog,
    float4* __restrict__ P4, float4* __restrict__ Q4){
  int tc = blockIdx.x;                 // 8 t-chunks of 64
  int dgrp = blockIdx.y;               // 4 groups of 256 d
  int b = blockIdx.z;                  // 8
  int tid = threadIdx.x;               // 256
  int d = dgrp*256 + tid;
  __shared__ float sD[64][68];         // dbl rows: cols 0-31 dt_low, 32-47 B, 48-63 C
  #pragma unroll
  for(int j=0;j<4;j++){
    int idx = j*256 + tid;
    int row = idx >> 4, q = idx & 15;
    float4 v = *(const float4*)(dbl + (size_t)(b*LL + tc*64 + row)*64 + q*4);
    *(float4*)(&sD[row][q*4]) = v;
  }
  float wdt[32];
  #pragma unroll
  for(int r4=0;r4<8;r4++){
    float4 v = *(const float4*)(dtw + (size_t)d*32 + r4*4);
    wdt[r4*4]=v.x; wdt[r4*4+1]=v.y; wdt[r4*4+2]=v.z; wdt[r4*4+3]=v.w;
  }
  float bias = dtb[d];
  float Ad[16];
  {
    float4 a0 = *(const float4*)(alog + d*16);
    float4 a1 = *(const float4*)(alog + d*16 + 4);
    float4 a2 = *(const float4*)(alog + d*16 + 8);
    float4 a3 = *(const float4*)(alog + d*16 + 12);
    Ad[0]=-__expf(a0.x); Ad[1]=-__expf(a0.y); Ad[2]=-__expf(a0.z); Ad[3]=-__expf(a0.w);
    Ad[4]=-__expf(a1.x); Ad[5]=-__expf(a1.y); Ad[6]=-__expf(a1.z); Ad[7]=-__expf(a1.w);
    Ad[8]=-__expf(a2.x); Ad[9]=-__expf(a2.y); Ad[10]=-__expf(a2.z); Ad[11]=-__expf(a2.w);
    Ad[12]=-__expf(a3.x); Ad[13]=-__expf(a3.y); Ad[14]=-__expf(a3.z); Ad[15]=-__expf(a3.w);
  }
  __syncthreads();
  float h[16];
  #pragma unroll
  for(int n=0;n<16;n++) h[n] = 0.f;
  float Ss = 0.f;
  const ushortT* up = ubf + (size_t)(b*LL + tc*64)*1024 + d;
  #pragma unroll 2
  for(int t=0;t<64;t++){
    float acc = bias;
    #pragma unroll
    for(int r=0;r<32;r++) acc += sD[t][r]*wdt[r];
    float dtv = (acc > 20.f) ? acc : __logf(1.f + __expf(acc));
    float uv = bf2f(up[(size_t)t*1024]);
    float wt = dtv * uv;
    Ss += dtv;
    #pragma unroll
    for(int n=0;n<16;n++){
      float e = __expf(dtv * Ad[n]);
      h[n] = h[n]*e + wt*sD[t][32+n];
    }
  }
  size_t base4 = (size_t)(tc*8 + b)*4*1024 + d;
  #pragma unroll
  for(int n4=0;n4<4;n4++){
    Q4[base4 + n4*1024] = make_float4(h[n4*4], h[n4*4+1], h[n4*4+2], h[n4*4+3]);
    P4[base4 + n4*1024] = make_float4(__expf(Ss*Ad[n4*4]), __expf(Ss*Ad[n4*4+1]),
                                      __expf(Ss*Ad[n4*4+2]), __expf(Ss*Ad[n4*4+3]));
  }
}

// ---------------- combine chunks + z_last dot + C-dot + gating -> yv[b][d] ----------------
// 128 blocks x 64 thr; gid: b = gid>>10, d = gid&1023 (d fastest -> coalesced P/Q)
__global__ __launch_bounds__(64) void k_scan_combine(const float4* __restrict__ P4,
    const float4* __restrict__ Q4, const float* __restrict__ dbl,
    const ushortT* __restrict__ ubf, const ushortT* __restrict__ xbf,
    const ushortT* __restrict__ wbf, const float* __restrict__ Dp,
    float* __restrict__ yv){
  int gid = blockIdx.x*64 + threadIdx.x;   // 8192
  int b = gid >> 10, d = gid & 1023;
  // z_last: dot(xbf[b,511,:], wbf[1024+d,:]) over K=512
  const ushortT* xr = xbf + (size_t)(b*LL + LL-1)*512;
  const ushortT* wr = wbf + (size_t)(1024 + d)*512;
  float zl = 0.f;
  for(int k=0;k<512;k+=8){
    short8v xv = *(const short8v*)(xr + k);
    short8v wv = *(const short8v*)(wr + k);
    #pragma unroll
    for(int j=0;j<8;j++) zl += bf2f((ushortT)xv[j])*bf2f((ushortT)wv[j]);
  }
  float h[16];
  #pragma unroll
  for(int n=0;n<16;n++) h[n] = 0.f;
  #pragma unroll
  for(int c=0;c<NTC;c++){
    size_t base4 = (size_t)(c*8 + b)*4*1024 + d;
    #pragma unroll
    for(int n4=0;n4<4;n4++){
      float4 pv = P4[base4 + n4*1024];
      float4 qv = Q4[base4 + n4*1024];
      h[n4*4+0] = pv.x*h[n4*4+0] + qv.x;
      h[n4*4+1] = pv.y*h[n4*4+1] + qv.y;
      h[n4*4+2] = pv.z*h[n4*4+2] + qv.z;
      h[n4*4+3] = pv.w*h[n4*4+3] + qv.w;
    }
  }
  const float* Crow = dbl + (size_t)(b*LL + LL-1)*64 + 48;
  float y = 0.f;
  #pragma unroll
  for(int n=0;n<16;n++) y += Crow[n]*h[n];
  float ul = bf2f(ubf[(size_t)(b*LL + LL-1)*1024 + d]);
  float sz = zl / (1.f + __expf(-zl));
  yv[b*1024 + d] = (y + ul*Dp[d]) * sz;
}

// ---------------- out_proj (last step only): xout[8][512] ----------------
__global__ __launch_bounds__(256) void k_outproj(const float* __restrict__ yv,
    const float* __restrict__ W, float* __restrict__ xout){
  int tid = threadIdx.x;
  int j = blockIdx.x*8 + (tid>>5);     // 64 blocks -> 512 outputs
  int ks = tid & 31;
  float a[8] = {};
  #pragma unroll
  for(int t=0;t<8;t++){
    int k = ks*4 + t*128;
    float4 wv = *(const float4*)(W + (size_t)j*1024 + k);
    #pragma unroll
    for(int b=0;b<8;b++){
      float4 xv = *(const float4*)(yv + b*1024 + k);
      a[b] += xv.x*wv.x + xv.y*wv.y + xv.z*wv.z + xv.w*wv.w;
    }
  }
  #pragma unroll
  for(int b=0;b<8;b++){
    #pragma unroll
    for(int o=16;o>=1;o>>=1) a[b] += __shfl_xor(a[b], o);
  }
  if(ks==0){
    #pragma unroll
    for(int b=0;b<8;b++) xout[b*512 + j] = a[b];
  }
}

// ---------------- head + denorm -> out[8][96][7] ----------------
__global__ __launch_bounds__(256) void k_head(const float* __restrict__ xout,
    const float* __restrict__ W, const float* __restrict__ hb,
    const float* __restrict__ mean, const float* __restrict__ stdv,
    float* __restrict__ out){
  int tid = threadIdx.x;
  int o = blockIdx.x*8 + (tid>>5);     // 84 blocks -> 672 outputs
  int ks = tid & 31;
  float a[8] = {};
  #pragma unroll
  for(int t=0;t<4;t++){
    int k = ks*4 + t*128;
    float4 wv = *(const float4*)(W + (size_t)o*512 + k);
    #pragma unroll
    for(int b=0;b<8;b++){
      float4 xv = *(const float4*)(xout + b*512 + k);
      a[b] += xv.x*wv.x + xv.y*wv.y + xv.z*wv.z + xv.w*wv.w;
    }
  }
  #pragma unroll
  for(int b=0;b<8;b++){
    #pragma unroll
    for(int oo=16;oo>=1;oo>>=1) a[b] += __shfl_xor(a[b], oo);
  }
  if(ks==0){
    int c = o % 7;
    #pragma unroll
    for(int b=0;b<8;b++){
      float v = a[b] + hb[o];
      out[b*NOUTC + o] = v * stdv[b*CIN + c] + mean[b*CIN + c];
    }
  }
}

extern "C" void kernel_launch(void* const* d_in, const int* in_sizes, int n_in,
                              void* d_out, int out_size, void* d_ws, size_t ws_size,
                              hipStream_t stream) {
  const float* x_enc   = (const float*)d_in[0];
  const float* x_mark  = (const float*)d_in[1];
  const float* tconvw  = (const float*)d_in[4];
  const float* tempw   = (const float*)d_in[5];
  const float* inprojw = (const float*)d_in[6];
  const float* convw   = (const float*)d_in[7];
  const float* convb   = (const float*)d_in[8];
  const float* xprojw  = (const float*)d_in[9];
  const float* dtw     = (const float*)d_in[10];
  const float* dtb     = (const float*)d_in[11];
  const float* alog    = (const float*)d_in[12];
  const float* dpar    = (const float*)d_in[13];
  const float* outw    = (const float*)d_in[14];
  const float* headw   = (const float*)d_in[15];
  const float* headb   = (const float*)d_in[16];

  float* ws    = (float*)d_ws;
  float* mean  = ws;                          // 64
  float* stdv  = ws + 64;                     // 64
  float* xn    = ws + 128;                    // 28,672 -> 28,800
  ushortT* xbf = (ushortT*)(ws + 28800);      // [4096][512]  bf16 -> 1,077,376
  ushortT* wbf = (ushortT*)(ws + 1077376);    // [2048][512]  bf16 -> 1,601,664
  ushortT* xpwbf=(ushortT*)(ws + 1601664);    // [64][1024]   bf16 -> 1,634,432
  ushortT* xpbf= (ushortT*)(ws + 1634432);    // [4096][1024] bf16 -> 3,731,584
  ushortT* ubf = (ushortT*)(ws + 3731584);    // [4096][1024] bf16 -> 5,828,736
  float* dbl   = ws + 5828736;                // [4096][64]   f32 -> 6,090,880
  float4* P4   = (float4*)(ws + 6090880);     // 262,144 float4 -> 7,139,456
  float4* Q4   = (float4*)(ws + 7139456);     // 262,144 float4 -> 8,188,032
  float* yv    = ws + 8188032;                // 8,192 -> 8,196,224
  float* xout  = ws + 8196224;                // 4,096 -> 8,200,320
  float* out   = (float*)d_out;

  k_prep  <<<1144, 256, 0, stream>>>(inprojw, xprojw, x_enc, wbf, xpwbf, mean, stdv, xn);
  k_embed <<<512, 512, 0, stream>>>(xn, x_mark, tconvw, tempw, (__hip_bfloat16*)xbf);
  k_inproj_mfma<<<dim3(8, 32), 256, 0, stream>>>(xbf, wbf, xpbf);
  k_dwconv<<<256, 1024, 0, stream>>>(xpbf, convw, convb, ubf);
  k_xproj_mfma<<<64, 256, 0, stream>>>(ubf, xpwbf, dbl);
  k_scan_chunk<<<dim3(NTC, 4, 8), 256, 0, stream>>>(dbl, ubf, dtw, dtb, alog, P4, Q4);
  k_scan_combine<<<128, 64, 0, stream>>>(P4, Q4, dbl, ubf, xbf, wbf, dpar, yv);
  k_outproj<<<64, 256, 0, stream>>>(yv, outw, xout);
  k_head  <<<84, 256, 0, stream>>>(xout, headw, headb, mean, stdv, out);
}